// Round 5
// baseline (278.846 us; speedup 1.0000x reference)
//
#include <hip/hip_runtime.h>
#include <hip/hip_bf16.h>
#include <stdint.h>

#define NODES 50000
#define NEDGE 800000
#define TEDGE (NEDGE + NODES)
#define GBLK ((NODES + 63) / 64)  // gmfma row-tile blocks (782)
#define CSRB 64                   // csr blocks
#define CSRCH 13312               // edges per csr block (64*13312 >= 850000)
#define NRB 784                   // nodes owned per csr block (64*784 = 50176)
#define NRN 50176                 // padded node stride for cnt/basecnt rows

typedef unsigned short u16;
typedef unsigned int u32;
typedef unsigned long long u64;
typedef short s16x8 __attribute__((ext_vector_type(8)));
typedef float f32x4 __attribute__((ext_vector_type(4)));

__device__ __forceinline__ float bf2f(u16 v) {
  return __uint_as_float(((u32)v) << 16);
}
__device__ __forceinline__ u16 f2bf(float f) {
  u32 u = __float_as_uint(f);
  u32 r = (u + 0x7FFFu + ((u >> 16) & 1u)) >> 16;
  return (u16)r;
}
__device__ __forceinline__ float lo16f(u32 w) { return __uint_as_float(w << 16); }
__device__ __forceinline__ float hi16f(u32 w) { return __uint_as_float(w & 0xFFFF0000u); }
__device__ __forceinline__ float lrelu(float x) {
  return (x > 0.f) ? x : 0.2f * x;
}
__device__ __forceinline__ int clampn(int v) {
  return ((u32)v < NODES) ? v : 0;
}
// fb = "external float arrays are bf16"; else plain f32
__device__ __forceinline__ float load1(const void* p, size_t i, bool fb) {
  return fb ? bf2f(((const u16*)p)[i]) : ((const float*)p)[i];
}
// order-preserving float<->uint encoding for unsigned atomicMax
__device__ __forceinline__ u32 encf(float f) {
  u32 u = __float_as_uint(f);
  return (u & 0x80000000u) ? ~u : (u | 0x80000000u);
}
__device__ __forceinline__ float decf(u32 k) {
  u32 u = (k & 0x80000000u) ? (k & 0x7FFFFFFFu) : ~k;
  return __uint_as_float(u);
}

// ---------------- probe: flags + weight prep ----------------
// flags[0]: edge_index is int64; flags[1]: float arrays are bf16
// flags[2..4]: csr kernel phase counters (zeroed here every iteration)
// flags[8..31]: encoded per-head global maxes (3 layers)
// Weight prep writes FRAGMENT-MAJOR layouts so k_gmfma's B-loads are fully
// coalesced:   wtf[((nt*KS+ks)*64 + quad*16 + lrow)*8 + j] = W[k][n]
// with n = nt*16+lrow, k = ks*32+quad*8+j.  Also computes the fused
// attention-dot columns Wa[k][col] (col<H: W@a_src head col; col<2H:
// W@a_dst head col-H; cols 2H..15 zero), same fragment layout (NT=1).
__global__ __launch_bounds__(256) void k_probe(
    const int* __restrict__ ei, const u16* __restrict__ xs16,
    int* __restrict__ flags,
    const void* __restrict__ W1, const void* __restrict__ W2,
    const void* __restrict__ W3, const void* __restrict__ as1,
    const void* __restrict__ ad1, const void* __restrict__ as2,
    const void* __restrict__ ad2, const void* __restrict__ as3,
    const void* __restrict__ ad3, u16* __restrict__ wt1,
    u16* __restrict__ wt2, u16* __restrict__ wt3, u16* __restrict__ wa1,
    u16* __restrict__ wa2, u16* __restrict__ wa3) {
  __shared__ int sfb;
  int t = threadIdx.x;
  int g = blockIdx.x * 256 + t;
  if (blockIdx.x == 0 && t >= 2 && t < 32) flags[t] = 0;
  if (t < 64) {
    int big = 0;
#pragma unroll
    for (int k = 0; k < 4; ++k) {
      u32 ex = (xs16[2 * (t * 4 + k)] >> 7) & 0xFF;
      big += (ex >= 0x90);  // |v| >= 2^17: impossible for N(0,1) bf16
    }
#pragma unroll
    for (int off = 32; off >= 1; off >>= 1) big += __shfl_xor(big, off);
    if (t == 0) sfb = (big >= 8) ? 0 : 1;
    if (blockIdx.x == 0) {
      int odd = 0, even = 0;
#pragma unroll
      for (int k = 0; k < 4; ++k) {
        int idx = t + 64 * k;
        odd |= (ei[2 * idx + 1] != 0);
        even |= (ei[2 * idx] != 0);
      }
      u64 bo = __ballot(odd);
      u64 be = __ballot(even);
      if (t == 0) flags[0] = (bo == 0ull && be != 0ull) ? 1 : 0;
    }
  }
  __syncthreads();
  bool fb = sfb != 0;
  if (blockIdx.x == 0 && t == 0) flags[1] = fb ? 1 : 0;

  // fragment-major transpose store index for (n,k), given KS
  auto fidx = [](int n, int k, int KS) {
    int nt = n >> 4, lrow = n & 15, ks = k >> 5, quad = (k >> 3) & 3, j = k & 7;
    return ((size_t)((nt * KS + ks) * 64 + quad * 16 + lrow)) * 8 + j;
  };

  if (g < 16384) {                        // W1: 128(K) x 128(N), KS=4
    int n = g >> 7, k = g & 127;
    wt1[fidx(n, k, 4)] = f2bf(load1(W1, (size_t)k * 128 + n, fb));
  } else if (g < 24576) {                 // W2: 128(K) x 64(N), KS=4
    int r = g - 16384;
    int n = r >> 7, k = r & 127;
    wt2[fidx(n, k, 4)] = f2bf(load1(W2, (size_t)k * 64 + n, fb));
  } else if (g < 25600) {                 // W3: 64(K) x 16(N), KS=2
    int r = g - 24576;
    int n = r >> 6, k = r & 63;
    wt3[fidx(n, k, 2)] = f2bf(load1(W3, (size_t)k * 16 + n, fb));
  } else if (g < 27648) {                 // Wa1: 128(K) x 16 cols (8 real)
    int e = g - 25600;
    int n = e >> 7, k = e & 127;
    float v = 0.f;
    if (n < 8) {
      int head = (n < 4) ? n : n - 4;
      const void* av = (n < 4) ? as1 : ad1;
      for (int c = 0; c < 32; ++c)
        v += load1(W1, (size_t)k * 128 + head * 32 + c, fb) *
             load1(av, head * 32 + c, fb);
    }
    wa1[fidx(n, k, 4)] = (n < 8) ? f2bf(v) : (u16)0;
  } else if (g < 29696) {                 // Wa2: 128(K) x 16 cols (4 real)
    int e = g - 27648;
    int n = e >> 7, k = e & 127;
    float v = 0.f;
    if (n < 4) {
      int head = (n < 2) ? n : n - 2;
      const void* av = (n < 2) ? as2 : ad2;
      for (int c = 0; c < 32; ++c)
        v += load1(W2, (size_t)k * 64 + head * 32 + c, fb) *
             load1(av, head * 32 + c, fb);
    }
    wa2[fidx(n, k, 4)] = (n < 4) ? f2bf(v) : (u16)0;
  } else if (g < 30720) {                 // Wa3: 64(K) x 16 cols (2 real)
    int e = g - 29696;
    int n = e >> 6, k = e & 63;
    float v = 0.f;
    if (n < 2) {
      const void* av = (n < 1) ? as3 : ad3;
      for (int c = 0; c < 16; ++c)
        v += load1(W3, (size_t)k * 16 + c, fb) * load1(av, c, fb);
    }
    wa3[fidx(n, k, 2)] = (n < 2) ? f2bf(v) : (u16)0;
  }
}

// ---------------- CSR build WITHOUT global returning atomics --------------
// R4 evidence: 850K returning device-scope atomicAdds are THROUGHPUT-bound
// at the coherence point (~21/ns; ILP-8 didn't move it). Order within a dst
// bucket is semantically free, so replace arrival-order ranks with a
// deterministic chunked bijection, built from LDS atomics only:
//   Phase A: 64 blocks x 13312-edge chunks; LDS u16-packed histogram of the
//            FULL node range (100KB); per-edge local rank kept in registers.
//            Write per-chunk counts cnt[chunk][node] (6.4MB).
//   Phase B: (spin-barrier) each block owns 784 nodes; basecnt[chunk][node]
//            = prefix over chunks; deg -> block scan + partial exchange ->
//            rowptr. (k_scan's proven publish-then-spin pattern, 3x.)
//   Phase C: (spin-barrier) slot = rowptr[d] + basecnt[mychunk][d] + rank.
// Deadlock-safe: publish before spin; 64 blocks always co-resident.
__global__ __launch_bounds__(1024) void k_csr(const int* __restrict__ ei,
                                              const int* __restrict__ flags,
                                              u16* __restrict__ cnt,
                                              u16* __restrict__ basecnt,
                                              int* __restrict__ rowptr,
                                              int* __restrict__ parts,
                                              int* __restrict__ ctrs,
                                              u16* __restrict__ srcs) {
  __shared__ u32 hcnt[NRN / 2];  // packed u16 pairs, 100352 B
  __shared__ int swave[16];
  __shared__ int sbase, stot;
  int b = blockIdx.x, t = threadIdx.x;

  // ---- Phase A: chunk histogram + register ranks ----
  for (int i = t; i < NRN / 2; i += 1024) hcnt[i] = 0;
  __syncthreads();
  bool odd = flags[0] != 0;
  int ebase = b * CSRCH;
  int sv[13], dv[13], rk[13];
#pragma unroll
  for (int i = 0; i < 13; ++i) {
    int e = ebase + i * 1024 + t;
    int s = 0, d = 0, r = -1;
    if (e < TEDGE) {
      if (e < NEDGE) {
        if (odd) { s = ei[2 * e]; d = ei[2 * (NEDGE + e)]; }
        else { s = ei[e]; d = ei[NEDGE + e]; }
      } else {
        s = e - NEDGE; d = s;  // self loops
      }
      s = clampn(s); d = clampn(d);
      u32 old = atomicAdd(&hcnt[d >> 1], 1u << (16 * (d & 1)));
      r = (int)((old >> (16 * (d & 1))) & 0xFFFFu);
    }
    sv[i] = s; dv[i] = d; rk[i] = r;
  }
  __syncthreads();
  {  // write chunk counts (coalesced u32)
    u32* crow = (u32*)(cnt + (size_t)b * NRN);
    for (int i = t; i < NRN / 2; i += 1024) crow[i] = hcnt[i];
  }
  __syncthreads();
  if (t == 0) {
    __hip_atomic_fetch_add(&ctrs[0], 1, __ATOMIC_RELEASE,
                           __HIP_MEMORY_SCOPE_AGENT);
    while (__hip_atomic_load(&ctrs[0], __ATOMIC_ACQUIRE,
                             __HIP_MEMORY_SCOPE_AGENT) < CSRB)
      __builtin_amdgcn_s_sleep(2);
  }
  __syncthreads();

  // ---- Phase B: per-node chunk prefix + rowptr ----
  int dg = 0;
  int d0 = b * NRB + t;
  if (t < NRB && d0 < NODES) {
    int acc = 0;
    for (int s = 0; s < CSRB; ++s) {  // coalesced per-iteration
      u16 c = cnt[(size_t)s * NRN + d0];
      basecnt[(size_t)s * NRN + d0] = (u16)acc;
      acc += c;
    }
    dg = acc;
  }
  int lane = t & 63, w = t >> 6;
  int x = dg;
#pragma unroll
  for (int off = 1; off < 64; off <<= 1) {
    int y = __shfl_up(x, off);
    if (lane >= off) x += y;
  }
  if (lane == 63) swave[w] = x;
  __syncthreads();
  if (w == 0) {
    int wv = (lane < 16) ? swave[lane] : 0;
#pragma unroll
    for (int off = 1; off < 16; off <<= 1) {
      int y = __shfl_up(wv, off);
      if (lane >= off) wv += y;
    }
    if (lane == 15) {  // block total; publish BEFORE any wait
      __hip_atomic_store(&parts[b], wv, __ATOMIC_RELAXED,
                         __HIP_MEMORY_SCOPE_AGENT);
      __hip_atomic_fetch_add(&ctrs[1], 1, __ATOMIC_RELEASE,
                             __HIP_MEMORY_SCOPE_AGENT);
    }
    if (lane < 16) swave[lane] = wv;  // inclusive wave prefix
  }
  __syncthreads();
  if (t == 0) {
    while (__hip_atomic_load(&ctrs[1], __ATOMIC_ACQUIRE,
                             __HIP_MEMORY_SCOPE_AGENT) < CSRB)
      __builtin_amdgcn_s_sleep(2);
  }
  __syncthreads();
  if (w == 0) {
    int pv = (lane < CSRB) ? __hip_atomic_load(&parts[lane], __ATOMIC_RELAXED,
                                               __HIP_MEMORY_SCOPE_AGENT)
                           : 0;
    int pb = (lane < b) ? pv : 0;
#pragma unroll
    for (int off = 32; off >= 1; off >>= 1) {
      pb += __shfl_xor(pb, off);
      pv += __shfl_xor(pv, off);
    }
    if (lane == 0) { sbase = pb; stot = pv; }
  }
  __syncthreads();
  int excl = sbase + ((w == 0) ? 0 : swave[w - 1]) + (x - dg);
  if (t < NRB && d0 < NODES) rowptr[d0] = excl;
  if (b == 0 && t == 0) rowptr[NODES] = stot;
  __syncthreads();
  if (t == 0) {
    __hip_atomic_fetch_add(&ctrs[2], 1, __ATOMIC_RELEASE,
                           __HIP_MEMORY_SCOPE_AGENT);
    while (__hip_atomic_load(&ctrs[2], __ATOMIC_ACQUIRE,
                             __HIP_MEMORY_SCOPE_AGENT) < CSRB)
      __builtin_amdgcn_s_sleep(2);
  }
  __syncthreads();

  // ---- Phase C: scatter (edge data still in registers) ----
#pragma unroll
  for (int i = 0; i < 13; ++i) {
    int e = ebase + i * 1024 + t;
    if (e < TEDGE) {
      int d = dv[i];
      int pos = rowptr[d] + (int)basecnt[(size_t)b * NRN + d] + rk[i];
      srcs[pos] = (u16)sv[i];
    }
  }
}

// ---------------- MFMA GEMM tile + MFMA-fused attention dots (bf16) -------
// h[M,N] = x[M,K] @ W[K,N]. Attention dots come from ONE extra MFMA N-tile
// whose B is Wa = W @ a_blockdiag (precomputed in k_probe). A is LDS-staged
// with coalesced uint4 loads (+8 bf16 pad -> 2-way-only bank aliasing);
// B-frags are coalesced 16B/lane loads from fragment-major wtf/waf
// (L1-resident). 16 rows per wave, 64 rows per 256-thread block.
// Fragment maps (verified): A[m=lane&15][k=quad*8+j]; B[k=quad*8+j][n=lane&15];
// D[row=quad*4+reg][col=lane&15].
template <int K, int N, int H, bool XEXT>
__global__ __launch_bounds__(256) void k_gmfma(const void* __restrict__ xin,
                                               const u16* __restrict__ wtf,
                                               const u16* __restrict__ waf,
                                               u16* __restrict__ hout,
                                               float* __restrict__ asg,
                                               float* __restrict__ adg,
                                               u32* __restrict__ gm,
                                               const int* __restrict__ flags,
                                               int M) {
  constexpr int KP = K + 8;
  constexpr int NT = N / 16;
  constexpr int KS = K / 32;
  constexpr int KG = K / 8;
  __shared__ u16 xlds[64 * KP];
  __shared__ u32 lmax[2 * H];
  int t = threadIdx.x;
  int row0 = blockIdx.x * 64;
  bool fb = flags[1] != 0;
  if (t < 2 * H) lmax[t] = 0;

  bool xbf = XEXT ? fb : true;
  for (int i = t; i < 64 * KG; i += 256) {  // stage x rows (coalesced 16B)
    int r = i / KG, kg = i % KG;
    int grow = row0 + r;
    if (grow >= M) grow = M - 1;  // clamped rows duplicate row M-1 (harmless)
    if (xbf) {
      *(uint4*)&xlds[r * KP + kg * 8] =
          *(const uint4*)((const u16*)xin + (size_t)grow * K + kg * 8);
    } else {
      const float* gp = (const float*)xin + (size_t)grow * K + kg * 8;
      float4 f0 = *(const float4*)gp, f1 = *(const float4*)(gp + 4);
      *(ushort4*)&xlds[r * KP + kg * 8] =
          make_ushort4(f2bf(f0.x), f2bf(f0.y), f2bf(f0.z), f2bf(f0.w));
      *(ushort4*)&xlds[r * KP + kg * 8 + 4] =
          make_ushort4(f2bf(f1.x), f2bf(f1.y), f2bf(f1.z), f2bf(f1.w));
    }
  }
  __syncthreads();

  int lane = t & 63, w = t >> 6;
  int lrow = lane & 15, quad = lane >> 4;
  f32x4 acc[NT];
  f32x4 eacc = (f32x4){0.f, 0.f, 0.f, 0.f};
#pragma unroll
  for (int nt = 0; nt < NT; ++nt) acc[nt] = (f32x4){0.f, 0.f, 0.f, 0.f};

  const u16* xbase = xlds + (w * 16 + lrow) * KP + quad * 8;
#pragma unroll
  for (int ks = 0; ks < KS; ++ks) {
    s16x8 a = *(const s16x8*)(xbase + ks * 32);
    s16x8 be = *(const s16x8*)(waf + ((size_t)(ks * 64 + lane)) * 8);
    eacc = __builtin_amdgcn_mfma_f32_16x16x32_bf16(a, be, eacc, 0, 0, 0);
#pragma unroll
    for (int nt = 0; nt < NT; ++nt) {
      s16x8 b = *(const s16x8*)(wtf + ((size_t)((nt * KS + ks) * 64 + lane)) * 8);
      acc[nt] = __builtin_amdgcn_mfma_f32_16x16x32_bf16(a, b, acc[nt], 0, 0, 0);
    }
  }

  float pm = -3.4e38f;
  int baserow = row0 + w * 16 + quad * 4;
#pragma unroll
  for (int r = 0; r < 4; ++r) {
    int grow = baserow + r;
    if (grow < M) {
#pragma unroll
      for (int nt = 0; nt < NT; ++nt)
        hout[(size_t)grow * N + nt * 16 + lrow] = f2bf(acc[nt][r]);
      if (lrow < H) asg[grow * H + lrow] = eacc[r];
      else if (lrow < 2 * H) adg[grow * H + (lrow - H)] = eacc[r];
    }
    pm = fmaxf(pm, eacc[r]);  // rows >= M duplicate a real row: safe
  }
  if (lrow < 2 * H) atomicMax(&lmax[lrow], encf(pm));
  __syncthreads();
  if (t < 2 * H) atomicMax(&gm[t], lmax[t]);
}

// ---------------- fused softmax + aggregation ----------------
// 2 nodes per wave (32 lanes each), 8 nodes per block; one edge pass with
// global-bound softmax (alpha = exp(l-M)/sum exp(l-M), exact for any uniform
// upper bound M). Gather: L = HC/8 lanes per edge (8 bf16 ch, dwordx4),
// EPN = 32/L edges per group per node, UN groups in flight.
// NOTE (R6-R13 evidence): this kernel sits at a replicated-working-set floor
// (FETCH = 8 XCD x h-bytes at ~2.45 TB/s effective); edge-parallel, bucket-
// sort, and XCD-sliced variants all measured worse. Do not re-litigate
// without new counter evidence.
template <int H, int C, bool RELU, bool FINAL>
__global__ __launch_bounds__(256) void k_agg(const u16* __restrict__ hbuf,
                                             const float* __restrict__ asg,
                                             const float* __restrict__ adg,
                                             const int* __restrict__ rowptr,
                                             const u16* __restrict__ srcs,
                                             const void* __restrict__ bias,
                                             const int* __restrict__ flags,
                                             const u32* __restrict__ gm,
                                             void* __restrict__ outp, int n) {
  constexpr int HC = H * C;
  constexpr int L = HC / 8;               // lanes per edge row
  constexpr int EPN = 32 / L;             // edges per group (per node half)
  constexpr int UN = (4 * EPN <= 32) ? 4 : 2;  // groups in flight
  __shared__ u16 lds_s[4][64];
  __shared__ float lds_e[4][64][H];
  int lane = threadIdx.x & 63;
  int w = threadIdx.x >> 6;
  int nh = lane >> 5;                     // node half within wave
  int hl = lane & 31;                     // lane within half
  int node = blockIdx.x * 8 + w * 2 + nh;
  if (node >= n) node = n - 1;
  bool fb = flags[1] != 0;
  int start = rowptr[node], end = rowptr[node + 1];
  if (end < start || end - start > TEDGE) { start = 0; end = 0; }

  float adh[H], M[H];
#pragma unroll
  for (int h = 0; h < H; ++h) adh[h] = adg[node * H + h];
#pragma unroll
  for (int h = 0; h < H; ++h) M[h] = lrelu(decf(gm[h]) + decf(gm[H + h]));

  int sub = hl / L;                       // edge slot within group
  int cl = hl & (L - 1);
  int ch0 = cl * 8;
  int myhead = ch0 / C;
  int base = nh * 32;                     // this half's staging slots

  float den[H];
#pragma unroll
  for (int h = 0; h < H; ++h) den[h] = 0.f;
  float acc[UN][8];
#pragma unroll
  for (int u = 0; u < UN; ++u)
#pragma unroll
    for (int i = 0; i < 8; ++i) acc[u][i] = 0.f;

  for (int chunk = start; chunk < end; chunk += 32) {
    int e = chunk + hl;
    int s = 0;
    float ee[H];
#pragma unroll
    for (int h = 0; h < H; ++h) ee[h] = 0.f;
    if (e < end) {
      s = srcs[e];
      float av[H];
      if (H == 4) { float4 t4 = *(const float4*)(asg + s * 4);
        av[0] = t4.x; av[1] = t4.y; av[H > 2 ? 2 : 0] = t4.z; av[H > 3 ? 3 : 0] = t4.w; }
      else if (H == 2) { float2 t2 = *(const float2*)(asg + s * 2); av[0] = t2.x; av[1] = t2.y; }
      else av[0] = asg[s];
#pragma unroll
      for (int h = 0; h < H; ++h) {
        float x = __expf(lrelu(av[h] + adh[h]) - M[h]);  // arg <= 0 by bound
        ee[h] = x;
        den[h] += x;
      }
    }
    __builtin_amdgcn_wave_barrier();  // prior reads done before overwrite
    lds_s[w][lane] = (u16)s;
#pragma unroll
    for (int h = 0; h < H; ++h) lds_e[w][lane][h] = ee[h];
    __builtin_amdgcn_wave_barrier();

    int cn = min(32, end - chunk);
    for (int j = 0; j < cn; j += UN * EPN) {  // staged slots zero-padded
      int sx[UN];
      float ax[UN];
#pragma unroll
      for (int u = 0; u < UN; ++u) {
        int ei_ = base + j + u * EPN + sub;
        sx[u] = lds_s[w][ei_];
        ax[u] = lds_e[w][ei_][myhead];
      }
#pragma unroll
      for (int u = 0; u < UN; ++u) {
        uint4 v = *(const uint4*)(hbuf + (size_t)sx[u] * HC + ch0);
        acc[u][0] += ax[u] * lo16f(v.x); acc[u][1] += ax[u] * hi16f(v.x);
        acc[u][2] += ax[u] * lo16f(v.y); acc[u][3] += ax[u] * hi16f(v.y);
        acc[u][4] += ax[u] * lo16f(v.z); acc[u][5] += ax[u] * hi16f(v.z);
        acc[u][6] += ax[u] * lo16f(v.w); acc[u][7] += ax[u] * hi16f(v.w);
      }
    }
  }

  // reduce denominators within the 32-lane half
#pragma unroll
  for (int m = 16; m >= 1; m >>= 1) {
#pragma unroll
    for (int h = 0; h < H; ++h) den[h] += __shfl_xor(den[h], m);
  }
  // combine groups, then reduce channel accumulators across subs (within half)
  float tt[8];
#pragma unroll
  for (int i = 0; i < 8; ++i) {
    tt[i] = acc[0][i];
#pragma unroll
    for (int u = 1; u < UN; ++u) tt[i] += acc[u][i];
  }
#pragma unroll
  for (int m = L; m < 32; m <<= 1) {
#pragma unroll
    for (int i = 0; i < 8; ++i) tt[i] += __shfl_xor(tt[i], m);
  }

  if (sub == 0) {
    float inv = 1.f / (den[myhead] + 1e-16f);
    float o[8];
#pragma unroll
    for (int i = 0; i < 8; ++i) {
      o[i] = tt[i] * inv + load1(bias, ch0 + i, fb);
      if (RELU) o[i] = fmaxf(o[i], 0.f);
    }
    bool obf = FINAL ? fb : true;
    if (obf) {
      uint4 pk;
      pk.x = (u32)f2bf(o[0]) | ((u32)f2bf(o[1]) << 16);
      pk.y = (u32)f2bf(o[2]) | ((u32)f2bf(o[3]) << 16);
      pk.z = (u32)f2bf(o[4]) | ((u32)f2bf(o[5]) << 16);
      pk.w = (u32)f2bf(o[6]) | ((u32)f2bf(o[7]) << 16);
      *(uint4*)((u16*)outp + (size_t)node * HC + ch0) = pk;
    } else {
      float* op = (float*)outp + (size_t)node * HC + ch0;
      *(float4*)op = make_float4(o[0], o[1], o[2], o[3]);
      *(float4*)(op + 4) = make_float4(o[4], o[5], o[6], o[7]);
    }
  }
}

// ---------------- launch ----------------

extern "C" void kernel_launch(void* const* d_in, const int* in_sizes, int n_in,
                              void* d_out, int out_size, void* d_ws, size_t ws_size,
                              hipStream_t stream) {
  const void* x   = d_in[0];
  const int* ei   = (const int*)d_in[1];
  const void* W1  = d_in[2];
  const void* as1 = d_in[3];
  const void* ad1 = d_in[4];
  const void* b1  = d_in[5];
  const void* W2  = d_in[6];
  const void* as2 = d_in[7];
  const void* ad2 = d_in[8];
  const void* b2  = d_in[9];
  const void* W3  = d_in[10];
  const void* as3 = d_in[11];
  const void* ad3 = d_in[12];
  const void* b3  = d_in[13];

  char* w = (char*)d_ws;
  auto alloc = [&](size_t bytes) {
    char* p = w;
    w += (bytes + 255) & ~(size_t)255;
    return p;
  };
  int* flags    = (int*)alloc(256);
  int* parts    = (int*)alloc(256);
  int* rowptr   = (int*)alloc((size_t)(NODES + 1) * 4);
  u16* cnt      = (u16*)alloc((size_t)CSRB * NRN * 2);
  u16* basecnt  = (u16*)alloc((size_t)CSRB * NRN * 2);
  u16* srcs     = (u16*)alloc((size_t)TEDGE * 2);
  float* asg    = (float*)alloc((size_t)NODES * 4 * 4);
  float* adg    = (float*)alloc((size_t)NODES * 4 * 4);
  u16* wt1      = (u16*)alloc((size_t)128 * 128 * 2);
  u16* wt2      = (u16*)alloc((size_t)64 * 128 * 2);
  u16* wt3      = (u16*)alloc((size_t)16 * 64 * 2);
  u16* wa1      = (u16*)alloc((size_t)16 * 128 * 2);
  u16* wa2      = (u16*)alloc((size_t)16 * 128 * 2);
  u16* wa3      = (u16*)alloc((size_t)16 * 64 * 2);
  u16* hbuf     = (u16*)alloc((size_t)NODES * 128 * 2);
  u16* obuf     = (u16*)alloc((size_t)NODES * 128 * 2);

  u32* gm1 = (u32*)(flags + 8);
  u32* gm2 = (u32*)(flags + 16);
  u32* gm3 = (u32*)(flags + 24);

  int ablocks = (NODES + 7) / 8;

  // probe: flags + fragment-major weight transposes + Wa columns
  k_probe<<<(NODES + 255) / 256, 256, 0, stream>>>(
      ei, (const u16*)x, flags, W1, W2, W3, as1, ad1, as2, ad2, as3, ad3,
      wt1, wt2, wt3, wa1, wa2, wa3);
  // CSR build: no global returning atomics (LDS ranks + chunk prefix)
  k_csr<<<CSRB, 1024, 0, stream>>>(ei, flags, cnt, basecnt, rowptr, parts,
                                   flags + 2, srcs);
  // layer 1: 128 -> 4x32 concat, relu
  k_gmfma<128, 128, 4, true><<<GBLK, 256, 0, stream>>>(x, wt1, wa1, hbuf, asg, adg, gm1, flags, NODES);
  k_agg<4, 32, true, false><<<ablocks, 256, 0, stream>>>(hbuf, asg, adg, rowptr, srcs, b1, flags, gm1, obuf, NODES);
  // layer 2: 128 -> 2x32 concat, relu
  k_gmfma<128, 64, 2, false><<<GBLK, 256, 0, stream>>>(obuf, wt2, wa2, hbuf, asg, adg, gm2, flags, NODES);
  k_agg<2, 32, true, false><<<ablocks, 256, 0, stream>>>(hbuf, asg, adg, rowptr, srcs, b2, flags, gm2, obuf, NODES);
  // layer 3: 64 -> 1x16 mean(=identity), out dtype follows input dtype
  k_gmfma<64, 16, 1, false><<<GBLK, 256, 0, stream>>>(obuf, wt3, wa3, hbuf, asg, adg, gm3, flags, NODES);
  k_agg<1, 16, false, true><<<ablocks, 256, 0, stream>>>(hbuf, asg, adg, rowptr, srcs, b3, flags, gm3, d_out, NODES);
}

// Round 6
// 271.974 us; speedup vs baseline: 1.0253x; 1.0253x over previous
//
#include <hip/hip_runtime.h>
#include <hip/hip_bf16.h>
#include <stdint.h>

#define NODES 50000
#define NEDGE 800000
#define TEDGE (NEDGE + NODES)
#define SBLK 25                        // scan blocks (2048 elems each)
#define GBLK ((NODES + 63) / 64)       // gmfma row-tile blocks (782)
#define HBLK8 ((TEDGE + 2047) / 2048)  // hist blocks at 8 edges/thread (416)
#define BL1_TOT (3 * HBLK8)            // interleaved grid: 2 gmfma : 1 hist

typedef unsigned short u16;
typedef unsigned int u32;
typedef unsigned long long u64;
typedef short s16x8 __attribute__((ext_vector_type(8)));
typedef float f32x4 __attribute__((ext_vector_type(4)));

__device__ __forceinline__ float bf2f(u16 v) {
  return __uint_as_float(((u32)v) << 16);
}
__device__ __forceinline__ u16 f2bf(float f) {
  u32 u = __float_as_uint(f);
  u32 r = (u + 0x7FFFu + ((u >> 16) & 1u)) >> 16;
  return (u16)r;
}
__device__ __forceinline__ float lo16f(u32 w) { return __uint_as_float(w << 16); }
__device__ __forceinline__ float hi16f(u32 w) { return __uint_as_float(w & 0xFFFF0000u); }
__device__ __forceinline__ float lrelu(float x) {
  return (x > 0.f) ? x : 0.2f * x;
}
__device__ __forceinline__ int clampn(int v) {
  return ((u32)v < NODES) ? v : 0;
}
// fb = "external float arrays are bf16"; else plain f32
__device__ __forceinline__ float load1(const void* p, size_t i, bool fb) {
  return fb ? bf2f(((const u16*)p)[i]) : ((const float*)p)[i];
}
// order-preserving float<->uint encoding for unsigned atomicMax
__device__ __forceinline__ u32 encf(float f) {
  u32 u = __float_as_uint(f);
  return (u & 0x80000000u) ? ~u : (u | 0x80000000u);
}
__device__ __forceinline__ float decf(u32 k) {
  u32 u = (k & 0x80000000u) ? (k & 0x7FFFFFFFu) : ~k;
  return __uint_as_float(u);
}

// ---------------- probe: flags + deg8 zero + weight prep ----------------
// flags[0]: edge_index is int64; flags[1]: float arrays are bf16
// flags[2]: scan completion counter (zeroed here every iteration)
// flags[8..31]: encoded per-head global maxes (3 layers)
// Weight prep writes FRAGMENT-MAJOR layouts so k_gmfma's B-loads are fully
// coalesced:   wtf[((nt*KS+ks)*64 + quad*16 + lrow)*8 + j] = W[k][n]
// with n = nt*16+lrow, k = ks*32+quad*8+j.  Also computes the fused
// attention-dot columns Wa[k][col] (col<H: W@a_src head col; col<2H:
// W@a_dst head col-H; cols 2H..15 zero), same fragment layout (NT=1).
__global__ __launch_bounds__(256) void k_probe(
    const int* __restrict__ ei, const u16* __restrict__ xs16,
    int* __restrict__ flags, u32* __restrict__ deg8,
    const void* __restrict__ W1, const void* __restrict__ W2,
    const void* __restrict__ W3, const void* __restrict__ as1,
    const void* __restrict__ ad1, const void* __restrict__ as2,
    const void* __restrict__ ad2, const void* __restrict__ as3,
    const void* __restrict__ ad3, u16* __restrict__ wt1,
    u16* __restrict__ wt2, u16* __restrict__ wt3, u16* __restrict__ wa1,
    u16* __restrict__ wa2, u16* __restrict__ wa3) {
  __shared__ int sfb;
  int t = threadIdx.x;
  int g = blockIdx.x * 256 + t;
  if (g < NODES) {
#pragma unroll
    for (int x = 0; x < 8; ++x) deg8[(size_t)x * NODES + g] = 0;
  }
  if (blockIdx.x == 0 && t >= 2 && t < 32) flags[t] = 0;
  if (t < 64) {
    int big = 0;
#pragma unroll
    for (int k = 0; k < 4; ++k) {
      u32 ex = (xs16[2 * (t * 4 + k)] >> 7) & 0xFF;
      big += (ex >= 0x90);  // |v| >= 2^17: impossible for N(0,1) bf16
    }
#pragma unroll
    for (int off = 32; off >= 1; off >>= 1) big += __shfl_xor(big, off);
    if (t == 0) sfb = (big >= 8) ? 0 : 1;
    if (blockIdx.x == 0) {
      int odd = 0, even = 0;
#pragma unroll
      for (int k = 0; k < 4; ++k) {
        int idx = t + 64 * k;
        odd |= (ei[2 * idx + 1] != 0);
        even |= (ei[2 * idx] != 0);
      }
      u64 bo = __ballot(odd);
      u64 be = __ballot(even);
      if (t == 0) flags[0] = (bo == 0ull && be != 0ull) ? 1 : 0;
    }
  }
  __syncthreads();
  bool fb = sfb != 0;
  if (blockIdx.x == 0 && t == 0) flags[1] = fb ? 1 : 0;

  // fragment-major transpose store index for (n,k), given KS
  auto fidx = [](int n, int k, int KS) {
    int nt = n >> 4, lrow = n & 15, ks = k >> 5, quad = (k >> 3) & 3, j = k & 7;
    return ((size_t)((nt * KS + ks) * 64 + quad * 16 + lrow)) * 8 + j;
  };

  if (g < 16384) {                        // W1: 128(K) x 128(N), KS=4
    int n = g >> 7, k = g & 127;
    wt1[fidx(n, k, 4)] = f2bf(load1(W1, (size_t)k * 128 + n, fb));
  } else if (g < 24576) {                 // W2: 128(K) x 64(N), KS=4
    int r = g - 16384;
    int n = r >> 7, k = r & 127;
    wt2[fidx(n, k, 4)] = f2bf(load1(W2, (size_t)k * 64 + n, fb));
  } else if (g < 25600) {                 // W3: 64(K) x 16(N), KS=2
    int r = g - 24576;
    int n = r >> 6, k = r & 63;
    wt3[fidx(n, k, 2)] = f2bf(load1(W3, (size_t)k * 16 + n, fb));
  } else if (g < 27648) {                 // Wa1: 128(K) x 16 cols (8 real)
    int e = g - 25600;
    int n = e >> 7, k = e & 127;
    float v = 0.f;
    if (n < 8) {
      int head = (n < 4) ? n : n - 4;
      const void* av = (n < 4) ? as1 : ad1;
      for (int c = 0; c < 32; ++c)
        v += load1(W1, (size_t)k * 128 + head * 32 + c, fb) *
             load1(av, head * 32 + c, fb);
    }
    wa1[fidx(n, k, 4)] = (n < 8) ? f2bf(v) : (u16)0;
  } else if (g < 29696) {                 // Wa2: 128(K) x 16 cols (4 real)
    int e = g - 27648;
    int n = e >> 7, k = e & 127;
    float v = 0.f;
    if (n < 4) {
      int head = (n < 2) ? n : n - 2;
      const void* av = (n < 2) ? as2 : ad2;
      for (int c = 0; c < 32; ++c)
        v += load1(W2, (size_t)k * 64 + head * 32 + c, fb) *
             load1(av, head * 32 + c, fb);
    }
    wa2[fidx(n, k, 4)] = (n < 4) ? f2bf(v) : (u16)0;
  } else if (g < 30720) {                 // Wa3: 64(K) x 16 cols (2 real)
    int e = g - 29696;
    int n = e >> 6, k = e & 63;
    float v = 0.f;
    if (n < 2) {
      const void* av = (n < 1) ? as3 : ad3;
      for (int c = 0; c < 16; ++c)
        v += load1(W3, (size_t)k * 16 + c, fb) * load1(av, c, fb);
    }
    wa3[fidx(n, k, 2)] = (n < 2) ? f2bf(v) : (u16)0;
  }
}

// ---------------- MFMA GEMM tile + MFMA-fused attention dots (bf16) -------
// h[M,N] = x[M,K] @ W[K,N]. Attention dots come from ONE extra MFMA N-tile
// whose B is Wa = W @ a_blockdiag (precomputed in k_probe). A is LDS-staged
// with coalesced uint4 loads (+8 bf16 pad -> 2-way-only bank aliasing);
// B-frags are coalesced 16B/lane loads from fragment-major wtf/waf
// (L1-resident). 16 rows per wave, 64 rows per 256-thread block.
// Fragment maps (verified): A[m=lane&15][k=quad*8+j]; B[k=quad*8+j][n=lane&15];
// D[row=quad*4+reg][col=lane&15].
template <int K, int N, int H, bool XEXT>
__device__ __forceinline__ void gmfma_tile(const void* __restrict__ xin,
                                           const u16* __restrict__ wtf,
                                           const u16* __restrict__ waf,
                                           u16* __restrict__ hout,
                                           float* __restrict__ asg,
                                           float* __restrict__ adg,
                                           u32* __restrict__ gm,
                                           const int* __restrict__ flags,
                                           int M, int row0,
                                           u16* __restrict__ xlds,
                                           u32* __restrict__ lmax) {
  constexpr int KP = K + 8;
  constexpr int NT = N / 16;
  constexpr int KS = K / 32;
  constexpr int KG = K / 8;
  int t = threadIdx.x;
  bool fb = flags[1] != 0;
  if (t < 2 * H) lmax[t] = 0;

  bool xbf = XEXT ? fb : true;
  for (int i = t; i < 64 * KG; i += 256) {  // stage x rows (coalesced 16B)
    int r = i / KG, kg = i % KG;
    int grow = row0 + r;
    if (grow >= M) grow = M - 1;  // clamped rows duplicate row M-1 (harmless)
    if (xbf) {
      *(uint4*)&xlds[r * KP + kg * 8] =
          *(const uint4*)((const u16*)xin + (size_t)grow * K + kg * 8);
    } else {
      const float* gp = (const float*)xin + (size_t)grow * K + kg * 8;
      float4 f0 = *(const float4*)gp, f1 = *(const float4*)(gp + 4);
      *(ushort4*)&xlds[r * KP + kg * 8] =
          make_ushort4(f2bf(f0.x), f2bf(f0.y), f2bf(f0.z), f2bf(f0.w));
      *(ushort4*)&xlds[r * KP + kg * 8 + 4] =
          make_ushort4(f2bf(f1.x), f2bf(f1.y), f2bf(f1.z), f2bf(f1.w));
    }
  }
  __syncthreads();

  int lane = t & 63, w = t >> 6;
  int lrow = lane & 15, quad = lane >> 4;
  f32x4 acc[NT];
  f32x4 eacc = (f32x4){0.f, 0.f, 0.f, 0.f};
#pragma unroll
  for (int nt = 0; nt < NT; ++nt) acc[nt] = (f32x4){0.f, 0.f, 0.f, 0.f};

  const u16* xbase = xlds + (w * 16 + lrow) * KP + quad * 8;
#pragma unroll
  for (int ks = 0; ks < KS; ++ks) {
    s16x8 a = *(const s16x8*)(xbase + ks * 32);
    s16x8 be = *(const s16x8*)(waf + ((size_t)(ks * 64 + lane)) * 8);
    eacc = __builtin_amdgcn_mfma_f32_16x16x32_bf16(a, be, eacc, 0, 0, 0);
#pragma unroll
    for (int nt = 0; nt < NT; ++nt) {
      s16x8 b = *(const s16x8*)(wtf + ((size_t)((nt * KS + ks) * 64 + lane)) * 8);
      acc[nt] = __builtin_amdgcn_mfma_f32_16x16x32_bf16(a, b, acc[nt], 0, 0, 0);
    }
  }

  float pm = -3.4e38f;
  int baserow = row0 + w * 16 + quad * 4;
#pragma unroll
  for (int r = 0; r < 4; ++r) {
    int grow = baserow + r;
    if (grow < M) {
#pragma unroll
      for (int nt = 0; nt < NT; ++nt)
        hout[(size_t)grow * N + nt * 16 + lrow] = f2bf(acc[nt][r]);
      if (lrow < H) asg[grow * H + lrow] = eacc[r];
      else if (lrow < 2 * H) adg[grow * H + (lrow - H)] = eacc[r];
    }
    pm = fmaxf(pm, eacc[r]);  // rows >= M duplicate a real row: safe
  }
  if (lrow < 2 * H) atomicMax(&lmax[lrow], encf(pm));
  __syncthreads();
  if (t < 2 * H) atomicMax(&gm[t], lmax[t]);
}

template <int K, int N, int H, bool XEXT>
__global__ __launch_bounds__(256) void k_gmfma(const void* __restrict__ xin,
                                               const u16* __restrict__ wtf,
                                               const u16* __restrict__ waf,
                                               u16* __restrict__ hout,
                                               float* __restrict__ asg,
                                               float* __restrict__ adg,
                                               u32* __restrict__ gm,
                                               const int* __restrict__ flags,
                                               int M) {
  __shared__ u16 xlds[64 * (K + 8)];
  __shared__ u32 lmax[2 * H];
  gmfma_tile<K, N, H, XEXT>(xin, wtf, waf, hout, asg, adg, gm, flags, M,
                            blockIdx.x * 64, xlds, lmax);
}

// ---------------- fused: CSR histogram ∥ layer-1 GEMM, INTERLEAVED --------
// R3/R4 evidence: 850K returning DEVICE-scope atomicAdds are throughput-
// bound at the Infinity-Cache RMW point (~21/ns; ILP-8 didn't move it).
// Fix the EXECUTION POINT instead: WORKGROUP-scope atomics stay in the
// issuing XCD's L2 (no device-coherence escalation) -> 8 parallel atomic
// engines. Correct by construction: 8 private copies deg8[xcd][node]
// indexed by the hardware XCC_ID (s_getreg, HW-verified m09); blocks on one
// XCD share one L2 (coherent RMW), different XCDs never share a copy.
// End-of-kernel release flushes L2 -> k_scan sees all counts.
__global__ __launch_bounds__(256) void k_build_l1(
    const void* __restrict__ xin, const u16* __restrict__ wtf,
    const u16* __restrict__ waf, u16* __restrict__ hout,
    float* __restrict__ asg, float* __restrict__ adg, u32* __restrict__ gm,
    const int* __restrict__ flags, const int* __restrict__ ei,
    u32* __restrict__ deg8, u32* __restrict__ rkx, u32* __restrict__ sd) {
  __shared__ u16 xlds[64 * 136];
  __shared__ u32 lmax[8];
  int bi = blockIdx.x;
  int r3 = bi % 3;
  if (r3 == 2) {  // ---- hist role: 8 edges/thread, XCD-local atomics ----
    int hb = bi / 3;
    int base = hb * 2048 + threadIdx.x;
    bool odd = flags[0] != 0;
    u32 xcd;
    asm volatile("s_getreg_b32 %0, hwreg(HW_REG_XCC_ID)" : "=s"(xcd));
    xcd &= 7u;
    u32* mydeg = deg8 + (size_t)xcd * NODES;
    int sv[8], dv[8];
#pragma unroll
    for (int u = 0; u < 8; ++u) {
      int e = base + u * 256;
      int s = 0, d = 0;
      if (e < TEDGE) {
        if (e < NEDGE) {
          if (odd) { s = ei[2 * e]; d = ei[2 * (NEDGE + e)]; }
          else { s = ei[e]; d = ei[NEDGE + e]; }
        } else {
          s = e - NEDGE; d = s;  // self loops
        }
        s = clampn(s); d = clampn(d);
      }
      sv[u] = s; dv[u] = d;
    }
    u32 rk[8];
#pragma unroll
    for (int u = 0; u < 8; ++u) {  // L2-local returning RMW, 8 independent
      int e = base + u * 256;
      rk[u] = (e < TEDGE)
                  ? __hip_atomic_fetch_add(&mydeg[dv[u]], 1u, __ATOMIC_RELAXED,
                                           __HIP_MEMORY_SCOPE_WORKGROUP)
                  : 0u;
    }
#pragma unroll
    for (int u = 0; u < 8; ++u) {
      int e = base + u * 256;
      if (e < TEDGE) {
        sd[e] = (u32)sv[u] | ((u32)dv[u] << 16);
        rkx[e] = (rk[u] & 0xFFFFu) | (xcd << 16);
      }
    }
    return;
  }
  // ---- layer-1 GEMM role ----
  int gb = (bi / 3) * 2 + r3;
  if (gb >= GBLK) return;
  gmfma_tile<128, 128, 4, true>(xin, wtf, waf, hout, asg, adg, gm, flags,
                                NODES, gb * 64, xlds, lmax);
}

// ---------------- parallel exclusive scan (25 blocks, publish-then-spin) ---
// Folds the 8 XCD-local count copies: per node, base8[x][i] = prefix over
// copies, deg = total; then the proven publish-then-spin block scan.
__global__ __launch_bounds__(1024) void k_scan(const u32* __restrict__ deg8,
                                               u32* __restrict__ base8,
                                               int* __restrict__ rowptr,
                                               int* __restrict__ parts,
                                               int* __restrict__ counter) {
  __shared__ int swave[16];
  __shared__ int sbase, stot;
  int b = blockIdx.x, t = threadIdx.x;
  int lane = t & 63, w = t >> 6;
  int i0 = b * 2048 + t * 2;
  int v0 = 0, v1 = 0;
  if (i0 < NODES) {
    int acc = 0;
#pragma unroll
    for (int x = 0; x < 8; ++x) {
      base8[(size_t)x * NODES + i0] = (u32)acc;
      acc += (int)deg8[(size_t)x * NODES + i0];
    }
    v0 = acc;
  }
  if (i0 + 1 < NODES) {
    int acc = 0;
#pragma unroll
    for (int x = 0; x < 8; ++x) {
      base8[(size_t)x * NODES + i0 + 1] = (u32)acc;
      acc += (int)deg8[(size_t)x * NODES + i0 + 1];
    }
    v1 = acc;
  }
  int local = v0 + v1;
  int x = local;
#pragma unroll
  for (int off = 1; off < 64; off <<= 1) {
    int y = __shfl_up(x, off);
    if (lane >= off) x += y;
  }
  if (lane == 63) swave[w] = x;
  __syncthreads();
  if (w == 0) {
    int wv = (lane < 16) ? swave[lane] : 0;
#pragma unroll
    for (int off = 1; off < 16; off <<= 1) {
      int y = __shfl_up(wv, off);
      if (lane >= off) wv += y;
    }
    if (lane == 15) {  // block total; publish BEFORE any wait
      __hip_atomic_store(&parts[b], wv, __ATOMIC_RELAXED,
                         __HIP_MEMORY_SCOPE_AGENT);
      __hip_atomic_fetch_add(counter, 1, __ATOMIC_RELEASE,
                             __HIP_MEMORY_SCOPE_AGENT);
    }
    if (lane < 16) swave[lane] = wv;  // inclusive wave prefix
  }
  __syncthreads();
  if (t == 0) {
    while (__hip_atomic_load(counter, __ATOMIC_ACQUIRE,
                             __HIP_MEMORY_SCOPE_AGENT) < SBLK)
      __builtin_amdgcn_s_sleep(2);
  }
  __syncthreads();
  if (w == 0) {
    int pv = (lane < SBLK) ? __hip_atomic_load(&parts[lane], __ATOMIC_RELAXED,
                                               __HIP_MEMORY_SCOPE_AGENT)
                           : 0;
    int pb = (lane < b) ? pv : 0;
#pragma unroll
    for (int off = 32; off >= 1; off >>= 1) {
      pb += __shfl_xor(pb, off);
      pv += __shfl_xor(pv, off);
    }
    if (lane == 0) { sbase = pb; stot = pv; }
  }
  __syncthreads();
  int run = sbase + ((w == 0) ? 0 : swave[w - 1]) + (x - local);
  if (i0 < NODES) rowptr[i0] = run;
  if (i0 + 1 < NODES) rowptr[i0 + 1] = run + v0;
  if (b == 0 && t == 0) rowptr[NODES] = stot;
}

// 4 edges/thread ILP: slot = rowptr[d] + base8[xcd][d] + local rank.
__global__ __launch_bounds__(256) void k_scatter(const u32* __restrict__ sd,
                                                 const u32* __restrict__ rkx,
                                                 const u32* __restrict__ base8,
                                                 const int* __restrict__ rowptr,
                                                 u16* __restrict__ srcs) {
  int base = blockIdx.x * 1024 + threadIdx.x;
#pragma unroll
  for (int u = 0; u < 4; ++u) {
    int e = base + u * 256;
    if (e < TEDGE) {
      u32 v = sd[e], r = rkx[e];
      int d = (int)(v >> 16);
      int pos = rowptr[d] + (int)base8[(size_t)(r >> 16) * NODES + d] +
                (int)(r & 0xFFFFu);
      srcs[pos] = (u16)(v & 0xFFFFu);
    }
  }
}

// ---------------- fused softmax + aggregation ----------------
// 2 nodes per wave (32 lanes each), 8 nodes per block; one edge pass with
// global-bound softmax (alpha = exp(l-M)/sum exp(l-M), exact for any uniform
// upper bound M). Gather: L = HC/8 lanes per edge (8 bf16 ch, dwordx4),
// EPN = 32/L edges per group per node, UN groups in flight.
// NOTE (R6-R13 evidence): this kernel sits at a replicated-working-set floor
// (FETCH = 8 XCD x h-bytes at ~2.45 TB/s effective); edge-parallel, bucket-
// sort, and XCD-sliced variants all measured worse. Do not re-litigate
// without new counter evidence.
template <int H, int C, bool RELU, bool FINAL>
__global__ __launch_bounds__(256) void k_agg(const u16* __restrict__ hbuf,
                                             const float* __restrict__ asg,
                                             const float* __restrict__ adg,
                                             const int* __restrict__ rowptr,
                                             const u16* __restrict__ srcs,
                                             const void* __restrict__ bias,
                                             const int* __restrict__ flags,
                                             const u32* __restrict__ gm,
                                             void* __restrict__ outp, int n) {
  constexpr int HC = H * C;
  constexpr int L = HC / 8;               // lanes per edge row
  constexpr int EPN = 32 / L;             // edges per group (per node half)
  constexpr int UN = (4 * EPN <= 32) ? 4 : 2;  // groups in flight
  __shared__ u16 lds_s[4][64];
  __shared__ float lds_e[4][64][H];
  int lane = threadIdx.x & 63;
  int w = threadIdx.x >> 6;
  int nh = lane >> 5;                     // node half within wave
  int hl = lane & 31;                     // lane within half
  int node = blockIdx.x * 8 + w * 2 + nh;
  if (node >= n) node = n - 1;
  bool fb = flags[1] != 0;
  int start = rowptr[node], end = rowptr[node + 1];
  if (end < start || end - start > TEDGE) { start = 0; end = 0; }

  float adh[H], M[H];
#pragma unroll
  for (int h = 0; h < H; ++h) adh[h] = adg[node * H + h];
#pragma unroll
  for (int h = 0; h < H; ++h) M[h] = lrelu(decf(gm[h]) + decf(gm[H + h]));

  int sub = hl / L;                       // edge slot within group
  int cl = hl & (L - 1);
  int ch0 = cl * 8;
  int myhead = ch0 / C;
  int base = nh * 32;                     // this half's staging slots

  float den[H];
#pragma unroll
  for (int h = 0; h < H; ++h) den[h] = 0.f;
  float acc[UN][8];
#pragma unroll
  for (int u = 0; u < UN; ++u)
#pragma unroll
    for (int i = 0; i < 8; ++i) acc[u][i] = 0.f;

  for (int chunk = start; chunk < end; chunk += 32) {
    int e = chunk + hl;
    int s = 0;
    float ee[H];
#pragma unroll
    for (int h = 0; h < H; ++h) ee[h] = 0.f;
    if (e < end) {
      s = srcs[e];
      float av[H];
      if (H == 4) { float4 t4 = *(const float4*)(asg + s * 4);
        av[0] = t4.x; av[1] = t4.y; av[H > 2 ? 2 : 0] = t4.z; av[H > 3 ? 3 : 0] = t4.w; }
      else if (H == 2) { float2 t2 = *(const float2*)(asg + s * 2); av[0] = t2.x; av[1] = t2.y; }
      else av[0] = asg[s];
#pragma unroll
      for (int h = 0; h < H; ++h) {
        float x = __expf(lrelu(av[h] + adh[h]) - M[h]);  // arg <= 0 by bound
        ee[h] = x;
        den[h] += x;
      }
    }
    __builtin_amdgcn_wave_barrier();  // prior reads done before overwrite
    lds_s[w][lane] = (u16)s;
#pragma unroll
    for (int h = 0; h < H; ++h) lds_e[w][lane][h] = ee[h];
    __builtin_amdgcn_wave_barrier();

    int cn = min(32, end - chunk);
    for (int j = 0; j < cn; j += UN * EPN) {  // staged slots zero-padded
      int sx[UN];
      float ax[UN];
#pragma unroll
      for (int u = 0; u < UN; ++u) {
        int ei_ = base + j + u * EPN + sub;
        sx[u] = lds_s[w][ei_];
        ax[u] = lds_e[w][ei_][myhead];
      }
#pragma unroll
      for (int u = 0; u < UN; ++u) {
        uint4 v = *(const uint4*)(hbuf + (size_t)sx[u] * HC + ch0);
        acc[u][0] += ax[u] * lo16f(v.x); acc[u][1] += ax[u] * hi16f(v.x);
        acc[u][2] += ax[u] * lo16f(v.y); acc[u][3] += ax[u] * hi16f(v.y);
        acc[u][4] += ax[u] * lo16f(v.z); acc[u][5] += ax[u] * hi16f(v.z);
        acc[u][6] += ax[u] * lo16f(v.w); acc[u][7] += ax[u] * hi16f(v.w);
      }
    }
  }

  // reduce denominators within the 32-lane half
#pragma unroll
  for (int m = 16; m >= 1; m >>= 1) {
#pragma unroll
    for (int h = 0; h < H; ++h) den[h] += __shfl_xor(den[h], m);
  }
  // combine groups, then reduce channel accumulators across subs (within half)
  float tt[8];
#pragma unroll
  for (int i = 0; i < 8; ++i) {
    tt[i] = acc[0][i];
#pragma unroll
    for (int u = 1; u < UN; ++u) tt[i] += acc[u][i];
  }
#pragma unroll
  for (int m = L; m < 32; m <<= 1) {
#pragma unroll
    for (int i = 0; i < 8; ++i) tt[i] += __shfl_xor(tt[i], m);
  }

  if (sub == 0) {
    float inv = 1.f / (den[myhead] + 1e-16f);
    float o[8];
#pragma unroll
    for (int i = 0; i < 8; ++i) {
      o[i] = tt[i] * inv + load1(bias, ch0 + i, fb);
      if (RELU) o[i] = fmaxf(o[i], 0.f);
    }
    bool obf = FINAL ? fb : true;
    if (obf) {
      uint4 pk;
      pk.x = (u32)f2bf(o[0]) | ((u32)f2bf(o[1]) << 16);
      pk.y = (u32)f2bf(o[2]) | ((u32)f2bf(o[3]) << 16);
      pk.z = (u32)f2bf(o[4]) | ((u32)f2bf(o[5]) << 16);
      pk.w = (u32)f2bf(o[6]) | ((u32)f2bf(o[7]) << 16);
      *(uint4*)((u16*)outp + (size_t)node * HC + ch0) = pk;
    } else {
      float* op = (float*)outp + (size_t)node * HC + ch0;
      *(float4*)op = make_float4(o[0], o[1], o[2], o[3]);
      *(float4*)(op + 4) = make_float4(o[4], o[5], o[6], o[7]);
    }
  }
}

// ---------------- launch ----------------

extern "C" void kernel_launch(void* const* d_in, const int* in_sizes, int n_in,
                              void* d_out, int out_size, void* d_ws, size_t ws_size,
                              hipStream_t stream) {
  const void* x   = d_in[0];
  const int* ei   = (const int*)d_in[1];
  const void* W1  = d_in[2];
  const void* as1 = d_in[3];
  const void* ad1 = d_in[4];
  const void* b1  = d_in[5];
  const void* W2  = d_in[6];
  const void* as2 = d_in[7];
  const void* ad2 = d_in[8];
  const void* b2  = d_in[9];
  const void* W3  = d_in[10];
  const void* as3 = d_in[11];
  const void* ad3 = d_in[12];
  const void* b3  = d_in[13];

  char* w = (char*)d_ws;
  auto alloc = [&](size_t bytes) {
    char* p = w;
    w += (bytes + 255) & ~(size_t)255;
    return p;
  };
  int* flags    = (int*)alloc(256);
  int* parts    = (int*)alloc(256);
  u32* deg8     = (u32*)alloc((size_t)8 * NODES * 4);
  u32* base8    = (u32*)alloc((size_t)8 * NODES * 4);
  int* rowptr   = (int*)alloc((size_t)(NODES + 1) * 4);
  u32* rkx      = (u32*)alloc((size_t)TEDGE * 4);
  u32* sd       = (u32*)alloc((size_t)TEDGE * 4);
  u16* srcs     = (u16*)alloc((size_t)TEDGE * 2);
  float* asg    = (float*)alloc((size_t)NODES * 4 * 4);
  float* adg    = (float*)alloc((size_t)NODES * 4 * 4);
  u16* wt1      = (u16*)alloc((size_t)128 * 128 * 2);
  u16* wt2      = (u16*)alloc((size_t)64 * 128 * 2);
  u16* wt3      = (u16*)alloc((size_t)16 * 64 * 2);
  u16* wa1      = (u16*)alloc((size_t)16 * 128 * 2);
  u16* wa2      = (u16*)alloc((size_t)16 * 128 * 2);
  u16* wa3      = (u16*)alloc((size_t)16 * 64 * 2);
  u16* hbuf     = (u16*)alloc((size_t)NODES * 128 * 2);
  u16* obuf     = (u16*)alloc((size_t)NODES * 128 * 2);

  u32* gm1 = (u32*)(flags + 8);
  u32* gm2 = (u32*)(flags + 16);
  u32* gm3 = (u32*)(flags + 24);

  int ablocks = (NODES + 7) / 8;

  // probe: flags + deg8 zero + fragment-major weight transposes + Wa columns
  k_probe<<<(NODES + 255) / 256, 256, 0, stream>>>(
      ei, (const u16*)x, flags, deg8, W1, W2, W3, as1, ad1, as2, ad2, as3,
      ad3, wt1, wt2, wt3, wa1, wa2, wa3);
  // fused + interleaved: CSR histogram (XCD-local atomics) ∥ layer-1 GEMM
  k_build_l1<<<BL1_TOT, 256, 0, stream>>>(x, wt1, wa1, hbuf, asg, adg, gm1,
                                          flags, ei, deg8, rkx, sd);
  k_scan<<<SBLK, 1024, 0, stream>>>(deg8, base8, rowptr, parts, flags + 2);
  k_scatter<<<(TEDGE + 1023) / 1024, 256, 0, stream>>>(sd, rkx, base8, rowptr, srcs);

  // layer 1 aggregation: 4x32 concat, relu
  k_agg<4, 32, true, false><<<ablocks, 256, 0, stream>>>(hbuf, asg, adg, rowptr, srcs, b1, flags, gm1, obuf, NODES);
  // layer 2: 128 -> 2x32 concat, relu
  k_gmfma<128, 64, 2, false><<<GBLK, 256, 0, stream>>>(obuf, wt2, wa2, hbuf, asg, adg, gm2, flags, NODES);
  k_agg<2, 32, true, false><<<ablocks, 256, 0, stream>>>(hbuf, asg, adg, rowptr, srcs, b2, flags, gm2, obuf, NODES);
  // layer 3: 64 -> 1x16 mean(=identity), out dtype follows input dtype
  k_gmfma<64, 16, 1, false><<<GBLK, 256, 0, stream>>>(obuf, wt3, wa3, hbuf, asg, adg, gm3, flags, NODES);
  k_agg<1, 16, false, true><<<ablocks, 256, 0, stream>>>(hbuf, asg, adg, rowptr, srcs, b3, flags, gm3, d_out, NODES);
}

// Round 7
// 265.393 us; speedup vs baseline: 1.0507x; 1.0248x over previous
//
#include <hip/hip_runtime.h>
#include <hip/hip_bf16.h>
#include <stdint.h>

#define NODES 50000
#define NEDGE 800000
#define TEDGE (NEDGE + NODES)
#define SBLK 25                   // scan blocks (2048 elems each)
#define GBLK ((NODES + 63) / 64)  // gmfma row-tile blocks (782)
#define CHNK 64                   // CSR chunks
#define CSRCH 13312               // edges per chunk (64*13312 >= 850000)
#define HALFN 25088               // nodes per sibling half
#define NSTR (2 * HALFN)          // padded node stride (50176 >= NODES)

typedef unsigned short u16;
typedef unsigned int u32;
typedef unsigned long long u64;
typedef short s16x8 __attribute__((ext_vector_type(8)));
typedef float f32x4 __attribute__((ext_vector_type(4)));

__device__ __forceinline__ float bf2f(u16 v) {
  return __uint_as_float(((u32)v) << 16);
}
__device__ __forceinline__ u16 f2bf(float f) {
  u32 u = __float_as_uint(f);
  u32 r = (u + 0x7FFFu + ((u >> 16) & 1u)) >> 16;
  return (u16)r;
}
__device__ __forceinline__ float lo16f(u32 w) { return __uint_as_float(w << 16); }
__device__ __forceinline__ float hi16f(u32 w) { return __uint_as_float(w & 0xFFFF0000u); }
__device__ __forceinline__ float lrelu(float x) {
  return (x > 0.f) ? x : 0.2f * x;
}
__device__ __forceinline__ int clampn(int v) {
  return ((u32)v < NODES) ? v : 0;
}
// fb = "external float arrays are bf16"; else plain f32
__device__ __forceinline__ float load1(const void* p, size_t i, bool fb) {
  return fb ? bf2f(((const u16*)p)[i]) : ((const float*)p)[i];
}
// order-preserving float<->uint encoding for unsigned atomicMax
__device__ __forceinline__ u32 encf(float f) {
  u32 u = __float_as_uint(f);
  return (u & 0x80000000u) ? ~u : (u | 0x80000000u);
}
__device__ __forceinline__ float decf(u32 k) {
  u32 u = (k & 0x80000000u) ? (k & 0x7FFFFFFFu) : ~k;
  return __uint_as_float(u);
}

// ---------------- probe: flags + weight prep ----------------
// flags[0]: edge_index is int64; flags[1]: float arrays are bf16
// flags[2]: scan completion counter (zeroed here every iteration)
// flags[8..31]: encoded per-head global maxes (3 layers)
// Weight prep writes FRAGMENT-MAJOR layouts so k_gmfma's B-loads are fully
// coalesced:   wtf[((nt*KS+ks)*64 + quad*16 + lrow)*8 + j] = W[k][n]
// with n = nt*16+lrow, k = ks*32+quad*8+j.  Also computes the fused
// attention-dot columns Wa[k][col] (col<H: W@a_src head col; col<2H:
// W@a_dst head col-H; cols 2H..15 zero), same fragment layout (NT=1).
__global__ __launch_bounds__(256) void k_probe(
    const int* __restrict__ ei, const u16* __restrict__ xs16,
    int* __restrict__ flags,
    const void* __restrict__ W1, const void* __restrict__ W2,
    const void* __restrict__ W3, const void* __restrict__ as1,
    const void* __restrict__ ad1, const void* __restrict__ as2,
    const void* __restrict__ ad2, const void* __restrict__ as3,
    const void* __restrict__ ad3, u16* __restrict__ wt1,
    u16* __restrict__ wt2, u16* __restrict__ wt3, u16* __restrict__ wa1,
    u16* __restrict__ wa2, u16* __restrict__ wa3) {
  __shared__ int sfb;
  int t = threadIdx.x;
  int g = blockIdx.x * 256 + t;
  if (blockIdx.x == 0 && t >= 2 && t < 32) flags[t] = 0;
  if (t < 64) {
    int big = 0;
#pragma unroll
    for (int k = 0; k < 4; ++k) {
      u32 ex = (xs16[2 * (t * 4 + k)] >> 7) & 0xFF;
      big += (ex >= 0x90);  // |v| >= 2^17: impossible for N(0,1) bf16
    }
#pragma unroll
    for (int off = 32; off >= 1; off >>= 1) big += __shfl_xor(big, off);
    if (t == 0) sfb = (big >= 8) ? 0 : 1;
    if (blockIdx.x == 0) {
      int odd = 0, even = 0;
#pragma unroll
      for (int k = 0; k < 4; ++k) {
        int idx = t + 64 * k;
        odd |= (ei[2 * idx + 1] != 0);
        even |= (ei[2 * idx] != 0);
      }
      u64 bo = __ballot(odd);
      u64 be = __ballot(even);
      if (t == 0) flags[0] = (bo == 0ull && be != 0ull) ? 1 : 0;
    }
  }
  __syncthreads();
  bool fb = sfb != 0;
  if (blockIdx.x == 0 && t == 0) flags[1] = fb ? 1 : 0;

  // fragment-major transpose store index for (n,k), given KS
  auto fidx = [](int n, int k, int KS) {
    int nt = n >> 4, lrow = n & 15, ks = k >> 5, quad = (k >> 3) & 3, j = k & 7;
    return ((size_t)((nt * KS + ks) * 64 + quad * 16 + lrow)) * 8 + j;
  };

  if (g < 16384) {                        // W1: 128(K) x 128(N), KS=4
    int n = g >> 7, k = g & 127;
    wt1[fidx(n, k, 4)] = f2bf(load1(W1, (size_t)k * 128 + n, fb));
  } else if (g < 24576) {                 // W2: 128(K) x 64(N), KS=4
    int r = g - 16384;
    int n = r >> 7, k = r & 127;
    wt2[fidx(n, k, 4)] = f2bf(load1(W2, (size_t)k * 64 + n, fb));
  } else if (g < 25600) {                 // W3: 64(K) x 16(N), KS=2
    int r = g - 24576;
    int n = r >> 6, k = r & 63;
    wt3[fidx(n, k, 2)] = f2bf(load1(W3, (size_t)k * 16 + n, fb));
  } else if (g < 27648) {                 // Wa1: 128(K) x 16 cols (8 real)
    int e = g - 25600;
    int n = e >> 7, k = e & 127;
    float v = 0.f;
    if (n < 8) {
      int head = (n < 4) ? n : n - 4;
      const void* av = (n < 4) ? as1 : ad1;
      for (int c = 0; c < 32; ++c)
        v += load1(W1, (size_t)k * 128 + head * 32 + c, fb) *
             load1(av, head * 32 + c, fb);
    }
    wa1[fidx(n, k, 4)] = (n < 8) ? f2bf(v) : (u16)0;
  } else if (g < 29696) {                 // Wa2: 128(K) x 16 cols (4 real)
    int e = g - 27648;
    int n = e >> 7, k = e & 127;
    float v = 0.f;
    if (n < 4) {
      int head = (n < 2) ? n : n - 2;
      const void* av = (n < 2) ? as2 : ad2;
      for (int c = 0; c < 32; ++c)
        v += load1(W2, (size_t)k * 64 + head * 32 + c, fb) *
             load1(av, head * 32 + c, fb);
    }
    wa2[fidx(n, k, 4)] = (n < 4) ? f2bf(v) : (u16)0;
  } else if (g < 30720) {                 // Wa3: 64(K) x 16 cols (2 real)
    int e = g - 29696;
    int n = e >> 6, k = e & 63;
    float v = 0.f;
    if (n < 2) {
      const void* av = (n < 1) ? as3 : ad3;
      for (int c = 0; c < 16; ++c)
        v += load1(W3, (size_t)k * 16 + c, fb) * load1(av, c, fb);
    }
    wa3[fidx(n, k, 2)] = (n < 2) ? f2bf(v) : (u16)0;
  }
}

// ---------------- CSR phase A: chunked LDS histogram -----------------------
// R4/R6 evidence: 850K device-scope returning atomicAdds are hard-capped at
// ~21/ns regardless of scope/ILP. R5 evidence: LDS-chunked counting works but
// died at 9.4% occupancy (all phases inside 64 one-block-per-CU kernels,
// 807 GB/s). Fix: ONLY the histogram runs on big-LDS blocks (128 of them:
// sibling pairs per chunk, each owning half the node range -> 50KB LDS);
// fold/scan/scatter are separate full-machine launches.
// Rank within a dst bucket is semantically free (fp sum order only), so
// rank = (chunk, LDS-local rank) with basecnt giving the chunk offset.
__global__ __launch_bounds__(1024) void k_hista(const int* __restrict__ ei,
                                                const int* __restrict__ flags,
                                                u32* __restrict__ sd,
                                                u16* __restrict__ rank16,
                                                u16* __restrict__ cnt) {
  __shared__ u32 hcnt[HALFN / 2];  // packed u16 pairs, 50176 B
  int b = blockIdx.x;
  int c = b >> 1, half = b & 1;
  int t = threadIdx.x;
  for (int i = t; i < HALFN / 2; i += 1024) hcnt[i] = 0;
  __syncthreads();
  bool odd = flags[0] != 0;
  int ebase = c * CSRCH;
  int nlo = half * HALFN;
#pragma unroll
  for (int i = 0; i < 13; ++i) {
    int e = ebase + i * 1024 + t;
    if (e < TEDGE) {
      int s, d;
      if (e < NEDGE) {
        if (odd) { s = ei[2 * e]; d = ei[2 * (NEDGE + e)]; }
        else { s = ei[e]; d = ei[NEDGE + e]; }
      } else {
        s = e - NEDGE; d = s;  // self loops
      }
      s = clampn(s); d = clampn(d);
      if (half == 0) sd[e] = (u32)s | ((u32)d << 16);
      int li = d - nlo;
      if ((u32)li < HALFN) {  // this sibling owns d
        u32 old = atomicAdd(&hcnt[li >> 1], 1u << (16 * (li & 1)));
        rank16[e] = (u16)((old >> (16 * (li & 1))) & 0xFFFFu);
      }
    }
  }
  __syncthreads();
  // contiguous 50KB row write: cnt[c][nlo .. nlo+HALFN)
  u32* crow = (u32*)(cnt + (size_t)c * NSTR + nlo);
  for (int i = t; i < HALFN / 2; i += 1024) crow[i] = hcnt[i];
}

// ---------------- CSR phase B1: fold chunk counts (full grid) --------------
// Per node: prefix over the 64 chunk counts -> basecnt[c][n], total -> deg.
// [chunk][node] layout makes every load/store lane-contiguous.
__global__ __launch_bounds__(256) void k_fold(const u16* __restrict__ cnt,
                                              u16* __restrict__ basecnt,
                                              int* __restrict__ deg) {
  int n = blockIdx.x * 256 + threadIdx.x;
  if (n >= NODES) return;
  int acc = 0;
#pragma unroll 8
  for (int c = 0; c < CHNK; ++c) {
    u16 v = cnt[(size_t)c * NSTR + n];
    basecnt[(size_t)c * NSTR + n] = (u16)acc;
    acc += v;
  }
  deg[n] = acc;
}

// ---------------- CSR phase B2: rowptr scan (25 blocks, publish-then-spin) -
__global__ __launch_bounds__(1024) void k_scan(const int* __restrict__ deg,
                                               int* __restrict__ rowptr,
                                               int* __restrict__ parts,
                                               int* __restrict__ counter) {
  __shared__ int swave[16];
  __shared__ int sbase, stot;
  int b = blockIdx.x, t = threadIdx.x;
  int lane = t & 63, w = t >> 6;
  int i0 = b * 2048 + t * 2;
  int v0 = (i0 < NODES) ? deg[i0] : 0;
  int v1 = (i0 + 1 < NODES) ? deg[i0 + 1] : 0;
  int local = v0 + v1;
  int x = local;
#pragma unroll
  for (int off = 1; off < 64; off <<= 1) {
    int y = __shfl_up(x, off);
    if (lane >= off) x += y;
  }
  if (lane == 63) swave[w] = x;
  __syncthreads();
  if (w == 0) {
    int wv = (lane < 16) ? swave[lane] : 0;
#pragma unroll
    for (int off = 1; off < 16; off <<= 1) {
      int y = __shfl_up(wv, off);
      if (lane >= off) wv += y;
    }
    if (lane == 15) {  // block total; publish BEFORE any wait
      __hip_atomic_store(&parts[b], wv, __ATOMIC_RELAXED,
                         __HIP_MEMORY_SCOPE_AGENT);
      __hip_atomic_fetch_add(counter, 1, __ATOMIC_RELEASE,
                             __HIP_MEMORY_SCOPE_AGENT);
    }
    if (lane < 16) swave[lane] = wv;  // inclusive wave prefix
  }
  __syncthreads();
  if (t == 0) {
    while (__hip_atomic_load(counter, __ATOMIC_ACQUIRE,
                             __HIP_MEMORY_SCOPE_AGENT) < SBLK)
      __builtin_amdgcn_s_sleep(2);
  }
  __syncthreads();
  if (w == 0) {
    int pv = (lane < SBLK) ? __hip_atomic_load(&parts[lane], __ATOMIC_RELAXED,
                                               __HIP_MEMORY_SCOPE_AGENT)
                           : 0;
    int pb = (lane < b) ? pv : 0;
#pragma unroll
    for (int off = 32; off >= 1; off >>= 1) {
      pb += __shfl_xor(pb, off);
      pv += __shfl_xor(pv, off);
    }
    if (lane == 0) { sbase = pb; stot = pv; }
  }
  __syncthreads();
  int run = sbase + ((w == 0) ? 0 : swave[w - 1]) + (x - local);
  if (i0 < NODES) rowptr[i0] = run;
  if (i0 + 1 < NODES) rowptr[i0 + 1] = run + v0;
  if (b == 0 && t == 0) rowptr[NODES] = stot;
}

// ---------------- CSR phase C: scatter, blocks grouped by chunk ------------
// Each block handles edges of ONE chunk, so its random basecnt reads stay in
// that chunk's L2-resident 100KB row. pos = rowptr[d] + basecnt[c][d] + rank.
__global__ __launch_bounds__(1024) void k_scatter(const u32* __restrict__ sd,
                                                  const u16* __restrict__ rank16,
                                                  const u16* __restrict__ basecnt,
                                                  const int* __restrict__ rowptr,
                                                  u16* __restrict__ srcs) {
  int c = blockIdx.x / 13;
  int r = blockIdx.x % 13;
  int e = c * CSRCH + r * 1024 + threadIdx.x;
  if (e >= TEDGE) return;
  u32 v = sd[e];
  int d = (int)(v >> 16);
  int pos = rowptr[d] + (int)basecnt[(size_t)c * NSTR + d] + (int)rank16[e];
  srcs[pos] = (u16)(v & 0xFFFFu);
}

// ---------------- MFMA GEMM tile + MFMA-fused attention dots (bf16) -------
// h[M,N] = x[M,K] @ W[K,N]. Attention dots come from ONE extra MFMA N-tile
// whose B is Wa = W @ a_blockdiag (precomputed in k_probe). A is LDS-staged
// with coalesced uint4 loads (+8 bf16 pad -> 2-way-only bank aliasing);
// B-frags are coalesced 16B/lane loads from fragment-major wtf/waf
// (L1-resident). 16 rows per wave, 64 rows per 256-thread block.
// Fragment maps (verified): A[m=lane&15][k=quad*8+j]; B[k=quad*8+j][n=lane&15];
// D[row=quad*4+reg][col=lane&15].
template <int K, int N, int H, bool XEXT>
__global__ __launch_bounds__(256) void k_gmfma(const void* __restrict__ xin,
                                               const u16* __restrict__ wtf,
                                               const u16* __restrict__ waf,
                                               u16* __restrict__ hout,
                                               float* __restrict__ asg,
                                               float* __restrict__ adg,
                                               u32* __restrict__ gm,
                                               const int* __restrict__ flags,
                                               int M) {
  constexpr int KP = K + 8;
  constexpr int NT = N / 16;
  constexpr int KS = K / 32;
  constexpr int KG = K / 8;
  __shared__ u16 xlds[64 * KP];
  __shared__ u32 lmax[2 * H];
  int t = threadIdx.x;
  int row0 = blockIdx.x * 64;
  bool fb = flags[1] != 0;
  if (t < 2 * H) lmax[t] = 0;

  bool xbf = XEXT ? fb : true;
  for (int i = t; i < 64 * KG; i += 256) {  // stage x rows (coalesced 16B)
    int r = i / KG, kg = i % KG;
    int grow = row0 + r;
    if (grow >= M) grow = M - 1;  // clamped rows duplicate row M-1 (harmless)
    if (xbf) {
      *(uint4*)&xlds[r * KP + kg * 8] =
          *(const uint4*)((const u16*)xin + (size_t)grow * K + kg * 8);
    } else {
      const float* gp = (const float*)xin + (size_t)grow * K + kg * 8;
      float4 f0 = *(const float4*)gp, f1 = *(const float4*)(gp + 4);
      *(ushort4*)&xlds[r * KP + kg * 8] =
          make_ushort4(f2bf(f0.x), f2bf(f0.y), f2bf(f0.z), f2bf(f0.w));
      *(ushort4*)&xlds[r * KP + kg * 8 + 4] =
          make_ushort4(f2bf(f1.x), f2bf(f1.y), f2bf(f1.z), f2bf(f1.w));
    }
  }
  __syncthreads();

  int lane = t & 63, w = t >> 6;
  int lrow = lane & 15, quad = lane >> 4;
  f32x4 acc[NT];
  f32x4 eacc = (f32x4){0.f, 0.f, 0.f, 0.f};
#pragma unroll
  for (int nt = 0; nt < NT; ++nt) acc[nt] = (f32x4){0.f, 0.f, 0.f, 0.f};

  const u16* xbase = xlds + (w * 16 + lrow) * KP + quad * 8;
#pragma unroll
  for (int ks = 0; ks < KS; ++ks) {
    s16x8 a = *(const s16x8*)(xbase + ks * 32);
    s16x8 be = *(const s16x8*)(waf + ((size_t)(ks * 64 + lane)) * 8);
    eacc = __builtin_amdgcn_mfma_f32_16x16x32_bf16(a, be, eacc, 0, 0, 0);
#pragma unroll
    for (int nt = 0; nt < NT; ++nt) {
      s16x8 b = *(const s16x8*)(wtf + ((size_t)((nt * KS + ks) * 64 + lane)) * 8);
      acc[nt] = __builtin_amdgcn_mfma_f32_16x16x32_bf16(a, b, acc[nt], 0, 0, 0);
    }
  }

  float pm = -3.4e38f;
  int baserow = row0 + w * 16 + quad * 4;
#pragma unroll
  for (int r = 0; r < 4; ++r) {
    int grow = baserow + r;
    if (grow < M) {
#pragma unroll
      for (int nt = 0; nt < NT; ++nt)
        hout[(size_t)grow * N + nt * 16 + lrow] = f2bf(acc[nt][r]);
      if (lrow < H) asg[grow * H + lrow] = eacc[r];
      else if (lrow < 2 * H) adg[grow * H + (lrow - H)] = eacc[r];
    }
    pm = fmaxf(pm, eacc[r]);  // rows >= M duplicate a real row: safe
  }
  if (lrow < 2 * H) atomicMax(&lmax[lrow], encf(pm));
  __syncthreads();
  if (t < 2 * H) atomicMax(&gm[t], lmax[t]);
}

// ---------------- fused softmax + aggregation ----------------
// 2 nodes per wave (32 lanes each), 8 nodes per block; one edge pass with
// global-bound softmax (alpha = exp(l-M)/sum exp(l-M), exact for any uniform
// upper bound M). Gather: L = HC/8 lanes per edge (8 bf16 ch, dwordx4),
// EPN = 32/L edges per group per node, UN groups in flight.
// NOTE (R6-R13 evidence): this kernel sits at a replicated-working-set floor
// (FETCH = 8 XCD x h-bytes at ~2.45 TB/s effective); edge-parallel, bucket-
// sort, and XCD-sliced variants all measured worse. Do not re-litigate
// without new counter evidence.
template <int H, int C, bool RELU, bool FINAL>
__global__ __launch_bounds__(256) void k_agg(const u16* __restrict__ hbuf,
                                             const float* __restrict__ asg,
                                             const float* __restrict__ adg,
                                             const int* __restrict__ rowptr,
                                             const u16* __restrict__ srcs,
                                             const void* __restrict__ bias,
                                             const int* __restrict__ flags,
                                             const u32* __restrict__ gm,
                                             void* __restrict__ outp, int n) {
  constexpr int HC = H * C;
  constexpr int L = HC / 8;               // lanes per edge row
  constexpr int EPN = 32 / L;             // edges per group (per node half)
  constexpr int UN = (4 * EPN <= 32) ? 4 : 2;  // groups in flight
  __shared__ u16 lds_s[4][64];
  __shared__ float lds_e[4][64][H];
  int lane = threadIdx.x & 63;
  int w = threadIdx.x >> 6;
  int nh = lane >> 5;                     // node half within wave
  int hl = lane & 31;                     // lane within half
  int node = blockIdx.x * 8 + w * 2 + nh;
  if (node >= n) node = n - 1;
  bool fb = flags[1] != 0;
  int start = rowptr[node], end = rowptr[node + 1];
  if (end < start || end - start > TEDGE) { start = 0; end = 0; }

  float adh[H], M[H];
#pragma unroll
  for (int h = 0; h < H; ++h) adh[h] = adg[node * H + h];
#pragma unroll
  for (int h = 0; h < H; ++h) M[h] = lrelu(decf(gm[h]) + decf(gm[H + h]));

  int sub = hl / L;                       // edge slot within group
  int cl = hl & (L - 1);
  int ch0 = cl * 8;
  int myhead = ch0 / C;
  int base = nh * 32;                     // this half's staging slots

  float den[H];
#pragma unroll
  for (int h = 0; h < H; ++h) den[h] = 0.f;
  float acc[UN][8];
#pragma unroll
  for (int u = 0; u < UN; ++u)
#pragma unroll
    for (int i = 0; i < 8; ++i) acc[u][i] = 0.f;

  for (int chunk = start; chunk < end; chunk += 32) {
    int e = chunk + hl;
    int s = 0;
    float ee[H];
#pragma unroll
    for (int h = 0; h < H; ++h) ee[h] = 0.f;
    if (e < end) {
      s = srcs[e];
      float av[H];
      if (H == 4) { float4 t4 = *(const float4*)(asg + s * 4);
        av[0] = t4.x; av[1] = t4.y; av[H > 2 ? 2 : 0] = t4.z; av[H > 3 ? 3 : 0] = t4.w; }
      else if (H == 2) { float2 t2 = *(const float2*)(asg + s * 2); av[0] = t2.x; av[1] = t2.y; }
      else av[0] = asg[s];
#pragma unroll
      for (int h = 0; h < H; ++h) {
        float x = __expf(lrelu(av[h] + adh[h]) - M[h]);  // arg <= 0 by bound
        ee[h] = x;
        den[h] += x;
      }
    }
    __builtin_amdgcn_wave_barrier();  // prior reads done before overwrite
    lds_s[w][lane] = (u16)s;
#pragma unroll
    for (int h = 0; h < H; ++h) lds_e[w][lane][h] = ee[h];
    __builtin_amdgcn_wave_barrier();

    int cn = min(32, end - chunk);
    for (int j = 0; j < cn; j += UN * EPN) {  // staged slots zero-padded
      int sx[UN];
      float ax[UN];
#pragma unroll
      for (int u = 0; u < UN; ++u) {
        int ei_ = base + j + u * EPN + sub;
        sx[u] = lds_s[w][ei_];
        ax[u] = lds_e[w][ei_][myhead];
      }
#pragma unroll
      for (int u = 0; u < UN; ++u) {
        uint4 v = *(const uint4*)(hbuf + (size_t)sx[u] * HC + ch0);
        acc[u][0] += ax[u] * lo16f(v.x); acc[u][1] += ax[u] * hi16f(v.x);
        acc[u][2] += ax[u] * lo16f(v.y); acc[u][3] += ax[u] * hi16f(v.y);
        acc[u][4] += ax[u] * lo16f(v.z); acc[u][5] += ax[u] * hi16f(v.z);
        acc[u][6] += ax[u] * lo16f(v.w); acc[u][7] += ax[u] * hi16f(v.w);
      }
    }
  }

  // reduce denominators within the 32-lane half
#pragma unroll
  for (int m = 16; m >= 1; m >>= 1) {
#pragma unroll
    for (int h = 0; h < H; ++h) den[h] += __shfl_xor(den[h], m);
  }
  // combine groups, then reduce channel accumulators across subs (within half)
  float tt[8];
#pragma unroll
  for (int i = 0; i < 8; ++i) {
    tt[i] = acc[0][i];
#pragma unroll
    for (int u = 1; u < UN; ++u) tt[i] += acc[u][i];
  }
#pragma unroll
  for (int m = L; m < 32; m <<= 1) {
#pragma unroll
    for (int i = 0; i < 8; ++i) tt[i] += __shfl_xor(tt[i], m);
  }

  if (sub == 0) {
    float inv = 1.f / (den[myhead] + 1e-16f);
    float o[8];
#pragma unroll
    for (int i = 0; i < 8; ++i) {
      o[i] = tt[i] * inv + load1(bias, ch0 + i, fb);
      if (RELU) o[i] = fmaxf(o[i], 0.f);
    }
    bool obf = FINAL ? fb : true;
    if (obf) {
      uint4 pk;
      pk.x = (u32)f2bf(o[0]) | ((u32)f2bf(o[1]) << 16);
      pk.y = (u32)f2bf(o[2]) | ((u32)f2bf(o[3]) << 16);
      pk.z = (u32)f2bf(o[4]) | ((u32)f2bf(o[5]) << 16);
      pk.w = (u32)f2bf(o[6]) | ((u32)f2bf(o[7]) << 16);
      *(uint4*)((u16*)outp + (size_t)node * HC + ch0) = pk;
    } else {
      float* op = (float*)outp + (size_t)node * HC + ch0;
      *(float4*)op = make_float4(o[0], o[1], o[2], o[3]);
      *(float4*)(op + 4) = make_float4(o[4], o[5], o[6], o[7]);
    }
  }
}

// ---------------- launch ----------------

extern "C" void kernel_launch(void* const* d_in, const int* in_sizes, int n_in,
                              void* d_out, int out_size, void* d_ws, size_t ws_size,
                              hipStream_t stream) {
  const void* x   = d_in[0];
  const int* ei   = (const int*)d_in[1];
  const void* W1  = d_in[2];
  const void* as1 = d_in[3];
  const void* ad1 = d_in[4];
  const void* b1  = d_in[5];
  const void* W2  = d_in[6];
  const void* as2 = d_in[7];
  const void* ad2 = d_in[8];
  const void* b2  = d_in[9];
  const void* W3  = d_in[10];
  const void* as3 = d_in[11];
  const void* ad3 = d_in[12];
  const void* b3  = d_in[13];

  char* w = (char*)d_ws;
  auto alloc = [&](size_t bytes) {
    char* p = w;
    w += (bytes + 255) & ~(size_t)255;
    return p;
  };
  int* flags    = (int*)alloc(256);
  int* parts    = (int*)alloc(256);
  int* deg      = (int*)alloc((size_t)NODES * 4);
  int* rowptr   = (int*)alloc((size_t)(NODES + 1) * 4);
  u16* cnt      = (u16*)alloc((size_t)CHNK * NSTR * 2);
  u16* basecnt  = (u16*)alloc((size_t)CHNK * NSTR * 2);
  u32* sd       = (u32*)alloc((size_t)TEDGE * 4);
  u16* rank16   = (u16*)alloc((size_t)TEDGE * 2);
  u16* srcs     = (u16*)alloc((size_t)TEDGE * 2);
  float* asg    = (float*)alloc((size_t)NODES * 4 * 4);
  float* adg    = (float*)alloc((size_t)NODES * 4 * 4);
  u16* wt1      = (u16*)alloc((size_t)128 * 128 * 2);
  u16* wt2      = (u16*)alloc((size_t)64 * 128 * 2);
  u16* wt3      = (u16*)alloc((size_t)16 * 64 * 2);
  u16* wa1      = (u16*)alloc((size_t)16 * 128 * 2);
  u16* wa2      = (u16*)alloc((size_t)16 * 128 * 2);
  u16* wa3      = (u16*)alloc((size_t)16 * 64 * 2);
  u16* hbuf     = (u16*)alloc((size_t)NODES * 128 * 2);
  u16* obuf     = (u16*)alloc((size_t)NODES * 128 * 2);

  u32* gm1 = (u32*)(flags + 8);
  u32* gm2 = (u32*)(flags + 16);
  u32* gm3 = (u32*)(flags + 24);

  int ablocks = (NODES + 7) / 8;

  // probe: flags + fragment-major weight transposes + Wa columns
  k_probe<<<(NODES + 255) / 256, 256, 0, stream>>>(
      ei, (const u16*)x, flags, W1, W2, W3, as1, ad1, as2, ad2, as3, ad3,
      wt1, wt2, wt3, wa1, wa2, wa3);
  // CSR build: chunked LDS histogram -> fold -> rowptr scan -> scatter
  k_hista<<<2 * CHNK, 1024, 0, stream>>>(ei, flags, sd, rank16, cnt);
  k_fold<<<(NODES + 255) / 256, 256, 0, stream>>>(cnt, basecnt, deg);
  k_scan<<<SBLK, 1024, 0, stream>>>(deg, rowptr, parts, flags + 2);
  k_scatter<<<CHNK * 13, 1024, 0, stream>>>(sd, rank16, basecnt, rowptr, srcs);

  // layer 1: 128 -> 4x32 concat, relu
  k_gmfma<128, 128, 4, true><<<GBLK, 256, 0, stream>>>(x, wt1, wa1, hbuf, asg, adg, gm1, flags, NODES);
  k_agg<4, 32, true, false><<<ablocks, 256, 0, stream>>>(hbuf, asg, adg, rowptr, srcs, b1, flags, gm1, obuf, NODES);
  // layer 2: 128 -> 2x32 concat, relu
  k_gmfma<128, 64, 2, false><<<GBLK, 256, 0, stream>>>(obuf, wt2, wa2, hbuf, asg, adg, gm2, flags, NODES);
  k_agg<2, 32, true, false><<<ablocks, 256, 0, stream>>>(hbuf, asg, adg, rowptr, srcs, b2, flags, gm2, obuf, NODES);
  // layer 3: 64 -> 1x16 mean(=identity), out dtype follows input dtype
  k_gmfma<64, 16, 1, false><<<GBLK, 256, 0, stream>>>(obuf, wt3, wa3, hbuf, asg, adg, gm3, flags, NODES);
  k_agg<1, 16, false, true><<<ablocks, 256, 0, stream>>>(hbuf, asg, adg, rowptr, srcs, b3, flags, gm3, d_out, NODES);
}

// Round 8
// 255.308 us; speedup vs baseline: 1.0922x; 1.0395x over previous
//
#include <hip/hip_runtime.h>
#include <hip/hip_bf16.h>
#include <stdint.h>

#define NODES 50000
#define NEDGE 800000
#define TEDGE (NEDGE + NODES)
#define GBLK ((NODES + 63) / 64)  // gmfma row-tile blocks (782)
#define CHNK 64                   // CSR chunks
#define CSRCH 13312               // edges per chunk (64*13312 >= 850000)
#define HALFN 25088               // nodes per sibling half
#define NSTR (2 * HALFN)          // padded node stride (50176 >= NODES)
#define FSB 64                    // foldscan blocks (784 nodes each)
#define SCATB 832                 // scatter role blocks (64 chunks x 13)

typedef unsigned short u16;
typedef unsigned int u32;
typedef unsigned long long u64;
typedef short s16x8 __attribute__((ext_vector_type(8)));
typedef float f32x4 __attribute__((ext_vector_type(4)));

__device__ __forceinline__ float bf2f(u16 v) {
  return __uint_as_float(((u32)v) << 16);
}
__device__ __forceinline__ u16 f2bf(float f) {
  u32 u = __float_as_uint(f);
  u32 r = (u + 0x7FFFu + ((u >> 16) & 1u)) >> 16;
  return (u16)r;
}
__device__ __forceinline__ float lo16f(u32 w) { return __uint_as_float(w << 16); }
__device__ __forceinline__ float hi16f(u32 w) { return __uint_as_float(w & 0xFFFF0000u); }
__device__ __forceinline__ float lrelu(float x) {
  return (x > 0.f) ? x : 0.2f * x;
}
__device__ __forceinline__ int clampn(int v) {
  return ((u32)v < NODES) ? v : 0;
}
// fb = "external float arrays are bf16"; else plain f32
__device__ __forceinline__ float load1(const void* p, size_t i, bool fb) {
  return fb ? bf2f(((const u16*)p)[i]) : ((const float*)p)[i];
}
// order-preserving float<->uint encoding for unsigned atomicMax
__device__ __forceinline__ u32 encf(float f) {
  u32 u = __float_as_uint(f);
  return (u & 0x80000000u) ? ~u : (u | 0x80000000u);
}
__device__ __forceinline__ float decf(u32 k) {
  u32 u = (k & 0x80000000u) ? (k & 0x7FFFFFFFu) : ~k;
  return __uint_as_float(u);
}

// ---------------- probe: flags + weight prep ----------------
// flags[0]: edge_index is int64; flags[1]: float arrays are bf16
// flags[2]: foldscan completion counter (zeroed here every iteration)
// flags[8..31]: encoded per-head global maxes (3 layers)
// Weight prep writes FRAGMENT-MAJOR layouts so k_gmfma's B-loads are fully
// coalesced:   wtf[((nt*KS+ks)*64 + quad*16 + lrow)*8 + j] = W[k][n]
// with n = nt*16+lrow, k = ks*32+quad*8+j.  Also computes the fused
// attention-dot columns Wa[k][col] (col<H: W@a_src head col; col<2H:
// W@a_dst head col-H; cols 2H..15 zero), same fragment layout (NT=1).
__global__ __launch_bounds__(256) void k_probe(
    const int* __restrict__ ei, const u16* __restrict__ xs16,
    int* __restrict__ flags,
    const void* __restrict__ W1, const void* __restrict__ W2,
    const void* __restrict__ W3, const void* __restrict__ as1,
    const void* __restrict__ ad1, const void* __restrict__ as2,
    const void* __restrict__ ad2, const void* __restrict__ as3,
    const void* __restrict__ ad3, u16* __restrict__ wt1,
    u16* __restrict__ wt2, u16* __restrict__ wt3, u16* __restrict__ wa1,
    u16* __restrict__ wa2, u16* __restrict__ wa3) {
  __shared__ int sfb;
  int t = threadIdx.x;
  int g = blockIdx.x * 256 + t;
  if (blockIdx.x == 0 && t >= 2 && t < 32) flags[t] = 0;
  if (t < 64) {
    int big = 0;
#pragma unroll
    for (int k = 0; k < 4; ++k) {
      u32 ex = (xs16[2 * (t * 4 + k)] >> 7) & 0xFF;
      big += (ex >= 0x90);  // |v| >= 2^17: impossible for N(0,1) bf16
    }
#pragma unroll
    for (int off = 32; off >= 1; off >>= 1) big += __shfl_xor(big, off);
    if (t == 0) sfb = (big >= 8) ? 0 : 1;
    if (blockIdx.x == 0) {
      int odd = 0, even = 0;
#pragma unroll
      for (int k = 0; k < 4; ++k) {
        int idx = t + 64 * k;
        odd |= (ei[2 * idx + 1] != 0);
        even |= (ei[2 * idx] != 0);
      }
      u64 bo = __ballot(odd);
      u64 be = __ballot(even);
      if (t == 0) flags[0] = (bo == 0ull && be != 0ull) ? 1 : 0;
    }
  }
  __syncthreads();
  bool fb = sfb != 0;
  if (blockIdx.x == 0 && t == 0) flags[1] = fb ? 1 : 0;

  // fragment-major transpose store index for (n,k), given KS
  auto fidx = [](int n, int k, int KS) {
    int nt = n >> 4, lrow = n & 15, ks = k >> 5, quad = (k >> 3) & 3, j = k & 7;
    return ((size_t)((nt * KS + ks) * 64 + quad * 16 + lrow)) * 8 + j;
  };

  if (g < 16384) {                        // W1: 128(K) x 128(N), KS=4
    int n = g >> 7, k = g & 127;
    wt1[fidx(n, k, 4)] = f2bf(load1(W1, (size_t)k * 128 + n, fb));
  } else if (g < 24576) {                 // W2: 128(K) x 64(N), KS=4
    int r = g - 16384;
    int n = r >> 7, k = r & 127;
    wt2[fidx(n, k, 4)] = f2bf(load1(W2, (size_t)k * 64 + n, fb));
  } else if (g < 25600) {                 // W3: 64(K) x 16(N), KS=2
    int r = g - 24576;
    int n = r >> 6, k = r & 63;
    wt3[fidx(n, k, 2)] = f2bf(load1(W3, (size_t)k * 16 + n, fb));
  } else if (g < 27648) {                 // Wa1: 128(K) x 16 cols (8 real)
    int e = g - 25600;
    int n = e >> 7, k = e & 127;
    float v = 0.f;
    if (n < 8) {
      int head = (n < 4) ? n : n - 4;
      const void* av = (n < 4) ? as1 : ad1;
      for (int c = 0; c < 32; ++c)
        v += load1(W1, (size_t)k * 128 + head * 32 + c, fb) *
             load1(av, head * 32 + c, fb);
    }
    wa1[fidx(n, k, 4)] = (n < 8) ? f2bf(v) : (u16)0;
  } else if (g < 29696) {                 // Wa2: 128(K) x 16 cols (4 real)
    int e = g - 27648;
    int n = e >> 7, k = e & 127;
    float v = 0.f;
    if (n < 4) {
      int head = (n < 2) ? n : n - 2;
      const void* av = (n < 2) ? as2 : ad2;
      for (int c = 0; c < 32; ++c)
        v += load1(W2, (size_t)k * 64 + head * 32 + c, fb) *
             load1(av, head * 32 + c, fb);
    }
    wa2[fidx(n, k, 4)] = (n < 4) ? f2bf(v) : (u16)0;
  } else if (g < 30720) {                 // Wa3: 64(K) x 16 cols (2 real)
    int e = g - 29696;
    int n = e >> 6, k = e & 63;
    float v = 0.f;
    if (n < 2) {
      const void* av = (n < 1) ? as3 : ad3;
      for (int c = 0; c < 16; ++c)
        v += load1(W3, (size_t)k * 16 + c, fb) * load1(av, c, fb);
    }
    wa3[fidx(n, k, 2)] = (n < 2) ? f2bf(v) : (u16)0;
  }
}

// ---------------- CSR phase A: chunked LDS histogram -----------------------
// R4/R6 evidence: 850K device-scope returning atomicAdds are hard-capped at
// ~21/ns regardless of scope/ILP -> counting must be LDS-local. R5/R7
// evidence: only the histogram needs big-LDS blocks; everything else runs on
// full-machine grids. 128 blocks: sibling pairs per chunk, each owning half
// the node range (50KB LDS). Rank within a dst bucket is semantically free,
// so rank = (chunk, LDS-local rank) with basecnt giving the chunk offset.
__global__ __launch_bounds__(1024) void k_hista(const int* __restrict__ ei,
                                                const int* __restrict__ flags,
                                                u32* __restrict__ sd,
                                                u16* __restrict__ rank16,
                                                u16* __restrict__ cnt) {
  __shared__ u32 hcnt[HALFN / 2];  // packed u16 pairs, 50176 B
  int b = blockIdx.x;
  int c = b >> 1, half = b & 1;
  int t = threadIdx.x;
  for (int i = t; i < HALFN / 2; i += 1024) hcnt[i] = 0;
  __syncthreads();
  bool odd = flags[0] != 0;
  int ebase = c * CSRCH;
  int nlo = half * HALFN;
#pragma unroll
  for (int i = 0; i < 13; ++i) {
    int e = ebase + i * 1024 + t;
    if (e < TEDGE) {
      int s, d;
      if (e < NEDGE) {
        if (odd) { s = ei[2 * e]; d = ei[2 * (NEDGE + e)]; }
        else { s = ei[e]; d = ei[NEDGE + e]; }
      } else {
        s = e - NEDGE; d = s;  // self loops
      }
      s = clampn(s); d = clampn(d);
      if (half == 0) sd[e] = (u32)s | ((u32)d << 16);
      int li = d - nlo;
      if ((u32)li < HALFN) {  // this sibling owns d
        u32 old = atomicAdd(&hcnt[li >> 1], 1u << (16 * (li & 1)));
        rank16[e] = (u16)((old >> (16 * (li & 1))) & 0xFFFFu);
      }
    }
  }
  __syncthreads();
  // contiguous 50KB row write: cnt[c][nlo .. nlo+HALFN)
  u32* crow = (u32*)(cnt + (size_t)c * NSTR + nlo);
  for (int i = t; i < HALFN / 2; i += 1024) crow[i] = hcnt[i];
}

// ---------------- CSR phase B: fold + rowptr scan, ONE kernel --------------
// 64 blocks x 1024 threads; block b owns nodes [b*784, b*784+784). Each
// thread folds its node's 64 chunk counts (lane-contiguous loads/stores;
// fold output consumed in-block so no deg array), block-scans the 784
// degrees, publishes its total BEFORE spinning (deadlock-free), then offsets
// by the prefix of the 64 partials. Replaces k_fold + k_scan (R7).
__global__ __launch_bounds__(1024) void k_foldscan(const u16* __restrict__ cnt,
                                                   u16* __restrict__ basecnt,
                                                   int* __restrict__ rowptr,
                                                   int* __restrict__ parts,
                                                   int* __restrict__ counter) {
  __shared__ int swave[16];
  __shared__ int sbase, stot;
  int b = blockIdx.x, t = threadIdx.x;
  int n = b * 784 + t;
  int v = 0;
  if (t < 784 && n < NODES) {
    int acc = 0;
#pragma unroll 8
    for (int c = 0; c < CHNK; ++c) {
      u16 cv = cnt[(size_t)c * NSTR + n];
      basecnt[(size_t)c * NSTR + n] = (u16)acc;
      acc += cv;
    }
    v = acc;
  }
  int lane = t & 63, w = t >> 6;
  int x = v;
#pragma unroll
  for (int off = 1; off < 64; off <<= 1) {
    int y = __shfl_up(x, off);
    if (lane >= off) x += y;
  }
  if (lane == 63) swave[w] = x;
  __syncthreads();
  if (w == 0) {
    int wv = (lane < 16) ? swave[lane] : 0;
#pragma unroll
    for (int off = 1; off < 16; off <<= 1) {
      int y = __shfl_up(wv, off);
      if (lane >= off) wv += y;
    }
    if (lane == 15) {  // block total; publish BEFORE any wait
      __hip_atomic_store(&parts[b], wv, __ATOMIC_RELAXED,
                         __HIP_MEMORY_SCOPE_AGENT);
      __hip_atomic_fetch_add(counter, 1, __ATOMIC_RELEASE,
                             __HIP_MEMORY_SCOPE_AGENT);
    }
    if (lane < 16) swave[lane] = wv;  // inclusive wave prefix
  }
  __syncthreads();
  if (t == 0) {
    while (__hip_atomic_load(counter, __ATOMIC_ACQUIRE,
                             __HIP_MEMORY_SCOPE_AGENT) < FSB)
      __builtin_amdgcn_s_sleep(2);
  }
  __syncthreads();
  if (w == 0) {  // 64 block partials, one wave
    int pv = __hip_atomic_load(&parts[lane], __ATOMIC_RELAXED,
                               __HIP_MEMORY_SCOPE_AGENT);
    int pb = (lane < b) ? pv : 0;
#pragma unroll
    for (int off = 32; off >= 1; off >>= 1) {
      pb += __shfl_xor(pb, off);
      pv += __shfl_xor(pv, off);
    }
    if (lane == 0) { sbase = pb; stot = pv; }
  }
  __syncthreads();
  int run = sbase + ((w == 0) ? 0 : swave[w - 1]) + (x - v);
  if (t < 784 && n < NODES) rowptr[n] = run;
  if (b == 0 && t == 0) rowptr[NODES] = stot;
}

// ---------------- CSR phase C ∥ layer-1 GEMM (role-split co-launch) --------
// Scatter and gmfma1 are independent (scatter: rowptr/basecnt/sd; gmfma1:
// x/wt1 from probe). 1614 blocks at 17.4KB LDS ≈ 6 blocks/CU -> BOTH roles
// resident simultaneously (unlike R3's 3321-block hist that filled the
// machine before the GEMM dispatched). Scatter keeps chunk-grouped basecnt
// L2 locality: 13 blocks per chunk exactly, c = idx/13.

template <int K, int N, int H, bool XEXT>
__device__ __forceinline__ void gmfma_tile(const void* __restrict__ xin,
                                           const u16* __restrict__ wtf,
                                           const u16* __restrict__ waf,
                                           u16* __restrict__ hout,
                                           float* __restrict__ asg,
                                           float* __restrict__ adg,
                                           u32* __restrict__ gm,
                                           const int* __restrict__ flags,
                                           int M, int row0,
                                           u16* __restrict__ xlds,
                                           u32* __restrict__ lmax) {
  constexpr int KP = K + 8;
  constexpr int NT = N / 16;
  constexpr int KS = K / 32;
  constexpr int KG = K / 8;
  int t = threadIdx.x;
  bool fb = flags[1] != 0;
  if (t < 2 * H) lmax[t] = 0;

  bool xbf = XEXT ? fb : true;
  for (int i = t; i < 64 * KG; i += 256) {  // stage x rows (coalesced 16B)
    int r = i / KG, kg = i % KG;
    int grow = row0 + r;
    if (grow >= M) grow = M - 1;  // clamped rows duplicate row M-1 (harmless)
    if (xbf) {
      *(uint4*)&xlds[r * KP + kg * 8] =
          *(const uint4*)((const u16*)xin + (size_t)grow * K + kg * 8);
    } else {
      const float* gp = (const float*)xin + (size_t)grow * K + kg * 8;
      float4 f0 = *(const float4*)gp, f1 = *(const float4*)(gp + 4);
      *(ushort4*)&xlds[r * KP + kg * 8] =
          make_ushort4(f2bf(f0.x), f2bf(f0.y), f2bf(f0.z), f2bf(f0.w));
      *(ushort4*)&xlds[r * KP + kg * 8 + 4] =
          make_ushort4(f2bf(f1.x), f2bf(f1.y), f2bf(f1.z), f2bf(f1.w));
    }
  }
  __syncthreads();

  int lane = t & 63, w = t >> 6;
  int lrow = lane & 15, quad = lane >> 4;
  f32x4 acc[NT];
  f32x4 eacc = (f32x4){0.f, 0.f, 0.f, 0.f};
#pragma unroll
  for (int nt = 0; nt < NT; ++nt) acc[nt] = (f32x4){0.f, 0.f, 0.f, 0.f};

  const u16* xbase = xlds + (w * 16 + lrow) * KP + quad * 8;
#pragma unroll
  for (int ks = 0; ks < KS; ++ks) {
    s16x8 a = *(const s16x8*)(xbase + ks * 32);
    s16x8 be = *(const s16x8*)(waf + ((size_t)(ks * 64 + lane)) * 8);
    eacc = __builtin_amdgcn_mfma_f32_16x16x32_bf16(a, be, eacc, 0, 0, 0);
#pragma unroll
    for (int nt = 0; nt < NT; ++nt) {
      s16x8 b = *(const s16x8*)(wtf + ((size_t)((nt * KS + ks) * 64 + lane)) * 8);
      acc[nt] = __builtin_amdgcn_mfma_f32_16x16x32_bf16(a, b, acc[nt], 0, 0, 0);
    }
  }

  float pm = -3.4e38f;
  int baserow = row0 + w * 16 + quad * 4;
#pragma unroll
  for (int r = 0; r < 4; ++r) {
    int grow = baserow + r;
    if (grow < M) {
#pragma unroll
      for (int nt = 0; nt < NT; ++nt)
        hout[(size_t)grow * N + nt * 16 + lrow] = f2bf(acc[nt][r]);
      if (lrow < H) asg[grow * H + lrow] = eacc[r];
      else if (lrow < 2 * H) adg[grow * H + (lrow - H)] = eacc[r];
    }
    pm = fmaxf(pm, eacc[r]);  // rows >= M duplicate a real row: safe
  }
  if (lrow < 2 * H) atomicMax(&lmax[lrow], encf(pm));
  __syncthreads();
  if (t < 2 * H) atomicMax(&gm[t], lmax[t]);
}

__global__ __launch_bounds__(256) void k_scatgm(
    const u32* __restrict__ sd, const u16* __restrict__ rank16,
    const u16* __restrict__ basecnt, const int* __restrict__ rowptr,
    u16* __restrict__ srcs, const void* __restrict__ xin,
    const u16* __restrict__ wtf, const u16* __restrict__ waf,
    u16* __restrict__ hout, float* __restrict__ asg, float* __restrict__ adg,
    u32* __restrict__ gm, const int* __restrict__ flags) {
  __shared__ u16 xlds[64 * 136];
  __shared__ u32 lmax[8];
  int bi = blockIdx.x;
  int role, idx;
  if (bi < 2 * GBLK) { role = bi & 1; idx = bi >> 1; }
  else { role = 0; idx = GBLK + (bi - 2 * GBLK); }  // trailing scatter blocks
  if (role == 0) {  // ---- scatter role: 4 edges/thread, chunk-grouped ----
    int c = idx / 13;
    int e0 = idx * 1024 + threadIdx.x;
#pragma unroll
    for (int u = 0; u < 4; ++u) {
      int e = e0 + u * 256;
      if (e < TEDGE) {
        u32 v = sd[e];
        int d = (int)(v >> 16);
        int pos = rowptr[d] + (int)basecnt[(size_t)c * NSTR + d] +
                  (int)rank16[e];
        srcs[pos] = (u16)(v & 0xFFFFu);
      }
    }
    return;
  }
  // ---- layer-1 GEMM role ----
  gmfma_tile<128, 128, 4, true>(xin, wtf, waf, hout, asg, adg, gm, flags,
                                NODES, idx * 64, xlds, lmax);
}

template <int K, int N, int H, bool XEXT>
__global__ __launch_bounds__(256) void k_gmfma(const void* __restrict__ xin,
                                               const u16* __restrict__ wtf,
                                               const u16* __restrict__ waf,
                                               u16* __restrict__ hout,
                                               float* __restrict__ asg,
                                               float* __restrict__ adg,
                                               u32* __restrict__ gm,
                                               const int* __restrict__ flags,
                                               int M) {
  __shared__ u16 xlds[64 * (K + 8)];
  __shared__ u32 lmax[2 * H];
  gmfma_tile<K, N, H, XEXT>(xin, wtf, waf, hout, asg, adg, gm, flags, M,
                            blockIdx.x * 64, xlds, lmax);
}

// ---------------- fused softmax + aggregation ----------------
// 2 nodes per wave (32 lanes each), 8 nodes per block; one edge pass with
// global-bound softmax (alpha = exp(l-M)/sum exp(l-M), exact for any uniform
// upper bound M). Gather: L = HC/8 lanes per edge (8 bf16 ch, dwordx4),
// EPN = 32/L edges per group per node, UN groups in flight.
// NOTE (R6-R13 evidence): this kernel sits at a replicated-working-set floor
// (FETCH = 8 XCD x h-bytes at ~2.45 TB/s effective); edge-parallel, bucket-
// sort, and XCD-sliced variants all measured worse. Do not re-litigate
// without new counter evidence.
template <int H, int C, bool RELU, bool FINAL>
__global__ __launch_bounds__(256) void k_agg(const u16* __restrict__ hbuf,
                                             const float* __restrict__ asg,
                                             const float* __restrict__ adg,
                                             const int* __restrict__ rowptr,
                                             const u16* __restrict__ srcs,
                                             const void* __restrict__ bias,
                                             const int* __restrict__ flags,
                                             const u32* __restrict__ gm,
                                             void* __restrict__ outp, int n) {
  constexpr int HC = H * C;
  constexpr int L = HC / 8;               // lanes per edge row
  constexpr int EPN = 32 / L;             // edges per group (per node half)
  constexpr int UN = (4 * EPN <= 32) ? 4 : 2;  // groups in flight
  __shared__ u16 lds_s[4][64];
  __shared__ float lds_e[4][64][H];
  int lane = threadIdx.x & 63;
  int w = threadIdx.x >> 6;
  int nh = lane >> 5;                     // node half within wave
  int hl = lane & 31;                     // lane within half
  int node = blockIdx.x * 8 + w * 2 + nh;
  if (node >= n) node = n - 1;
  bool fb = flags[1] != 0;
  int start = rowptr[node], end = rowptr[node + 1];
  if (end < start || end - start > TEDGE) { start = 0; end = 0; }

  float adh[H], M[H];
#pragma unroll
  for (int h = 0; h < H; ++h) adh[h] = adg[node * H + h];
#pragma unroll
  for (int h = 0; h < H; ++h) M[h] = lrelu(decf(gm[h]) + decf(gm[H + h]));

  int sub = hl / L;                       // edge slot within group
  int cl = hl & (L - 1);
  int ch0 = cl * 8;
  int myhead = ch0 / C;
  int base = nh * 32;                     // this half's staging slots

  float den[H];
#pragma unroll
  for (int h = 0; h < H; ++h) den[h] = 0.f;
  float acc[UN][8];
#pragma unroll
  for (int u = 0; u < UN; ++u)
#pragma unroll
    for (int i = 0; i < 8; ++i) acc[u][i] = 0.f;

  for (int chunk = start; chunk < end; chunk += 32) {
    int e = chunk + hl;
    int s = 0;
    float ee[H];
#pragma unroll
    for (int h = 0; h < H; ++h) ee[h] = 0.f;
    if (e < end) {
      s = srcs[e];
      float av[H];
      if (H == 4) { float4 t4 = *(const float4*)(asg + s * 4);
        av[0] = t4.x; av[1] = t4.y; av[H > 2 ? 2 : 0] = t4.z; av[H > 3 ? 3 : 0] = t4.w; }
      else if (H == 2) { float2 t2 = *(const float2*)(asg + s * 2); av[0] = t2.x; av[1] = t2.y; }
      else av[0] = asg[s];
#pragma unroll
      for (int h = 0; h < H; ++h) {
        float x = __expf(lrelu(av[h] + adh[h]) - M[h]);  // arg <= 0 by bound
        ee[h] = x;
        den[h] += x;
      }
    }
    __builtin_amdgcn_wave_barrier();  // prior reads done before overwrite
    lds_s[w][lane] = (u16)s;
#pragma unroll
    for (int h = 0; h < H; ++h) lds_e[w][lane][h] = ee[h];
    __builtin_amdgcn_wave_barrier();

    int cn = min(32, end - chunk);
    for (int j = 0; j < cn; j += UN * EPN) {  // staged slots zero-padded
      int sx[UN];
      float ax[UN];
#pragma unroll
      for (int u = 0; u < UN; ++u) {
        int ei_ = base + j + u * EPN + sub;
        sx[u] = lds_s[w][ei_];
        ax[u] = lds_e[w][ei_][myhead];
      }
#pragma unroll
      for (int u = 0; u < UN; ++u) {
        uint4 v = *(const uint4*)(hbuf + (size_t)sx[u] * HC + ch0);
        acc[u][0] += ax[u] * lo16f(v.x); acc[u][1] += ax[u] * hi16f(v.x);
        acc[u][2] += ax[u] * lo16f(v.y); acc[u][3] += ax[u] * hi16f(v.y);
        acc[u][4] += ax[u] * lo16f(v.z); acc[u][5] += ax[u] * hi16f(v.z);
        acc[u][6] += ax[u] * lo16f(v.w); acc[u][7] += ax[u] * hi16f(v.w);
      }
    }
  }

  // reduce denominators within the 32-lane half
#pragma unroll
  for (int m = 16; m >= 1; m >>= 1) {
#pragma unroll
    for (int h = 0; h < H; ++h) den[h] += __shfl_xor(den[h], m);
  }
  // combine groups, then reduce channel accumulators across subs (within half)
  float tt[8];
#pragma unroll
  for (int i = 0; i < 8; ++i) {
    tt[i] = acc[0][i];
#pragma unroll
    for (int u = 1; u < UN; ++u) tt[i] += acc[u][i];
  }
#pragma unroll
  for (int m = L; m < 32; m <<= 1) {
#pragma unroll
    for (int i = 0; i < 8; ++i) tt[i] += __shfl_xor(tt[i], m);
  }

  if (sub == 0) {
    float inv = 1.f / (den[myhead] + 1e-16f);
    float o[8];
#pragma unroll
    for (int i = 0; i < 8; ++i) {
      o[i] = tt[i] * inv + load1(bias, ch0 + i, fb);
      if (RELU) o[i] = fmaxf(o[i], 0.f);
    }
    bool obf = FINAL ? fb : true;
    if (obf) {
      uint4 pk;
      pk.x = (u32)f2bf(o[0]) | ((u32)f2bf(o[1]) << 16);
      pk.y = (u32)f2bf(o[2]) | ((u32)f2bf(o[3]) << 16);
      pk.z = (u32)f2bf(o[4]) | ((u32)f2bf(o[5]) << 16);
      pk.w = (u32)f2bf(o[6]) | ((u32)f2bf(o[7]) << 16);
      *(uint4*)((u16*)outp + (size_t)node * HC + ch0) = pk;
    } else {
      float* op = (float*)outp + (size_t)node * HC + ch0;
      *(float4*)op = make_float4(o[0], o[1], o[2], o[3]);
      *(float4*)(op + 4) = make_float4(o[4], o[5], o[6], o[7]);
    }
  }
}

// ---------------- launch ----------------

extern "C" void kernel_launch(void* const* d_in, const int* in_sizes, int n_in,
                              void* d_out, int out_size, void* d_ws, size_t ws_size,
                              hipStream_t stream) {
  const void* x   = d_in[0];
  const int* ei   = (const int*)d_in[1];
  const void* W1  = d_in[2];
  const void* as1 = d_in[3];
  const void* ad1 = d_in[4];
  const void* b1  = d_in[5];
  const void* W2  = d_in[6];
  const void* as2 = d_in[7];
  const void* ad2 = d_in[8];
  const void* b2  = d_in[9];
  const void* W3  = d_in[10];
  const void* as3 = d_in[11];
  const void* ad3 = d_in[12];
  const void* b3  = d_in[13];

  char* w = (char*)d_ws;
  auto alloc = [&](size_t bytes) {
    char* p = w;
    w += (bytes + 255) & ~(size_t)255;
    return p;
  };
  int* flags    = (int*)alloc(256);
  int* parts    = (int*)alloc(256);
  int* rowptr   = (int*)alloc((size_t)(NODES + 1) * 4);
  u16* cnt      = (u16*)alloc((size_t)CHNK * NSTR * 2);
  u16* basecnt  = (u16*)alloc((size_t)CHNK * NSTR * 2);
  u32* sd       = (u32*)alloc((size_t)TEDGE * 4);
  u16* rank16   = (u16*)alloc((size_t)TEDGE * 2);
  u16* srcs     = (u16*)alloc((size_t)TEDGE * 2);
  float* asg    = (float*)alloc((size_t)NODES * 4 * 4);
  float* adg    = (float*)alloc((size_t)NODES * 4 * 4);
  u16* wt1      = (u16*)alloc((size_t)128 * 128 * 2);
  u16* wt2      = (u16*)alloc((size_t)64 * 128 * 2);
  u16* wt3      = (u16*)alloc((size_t)16 * 64 * 2);
  u16* wa1      = (u16*)alloc((size_t)16 * 128 * 2);
  u16* wa2      = (u16*)alloc((size_t)16 * 128 * 2);
  u16* wa3      = (u16*)alloc((size_t)16 * 64 * 2);
  u16* hbuf     = (u16*)alloc((size_t)NODES * 128 * 2);
  u16* obuf     = (u16*)alloc((size_t)NODES * 128 * 2);

  u32* gm1 = (u32*)(flags + 8);
  u32* gm2 = (u32*)(flags + 16);
  u32* gm3 = (u32*)(flags + 24);

  int ablocks = (NODES + 7) / 8;
  int sgrid = 2 * GBLK + (SCATB - GBLK);  // 1614

  // probe: flags + fragment-major weight transposes + Wa columns
  k_probe<<<(NODES + 255) / 256, 256, 0, stream>>>(
      ei, (const u16*)x, flags, W1, W2, W3, as1, ad1, as2, ad2, as3, ad3,
      wt1, wt2, wt3, wa1, wa2, wa3);
  // CSR: chunked LDS histogram -> fused fold+scan -> scatter ∥ layer-1 GEMM
  k_hista<<<2 * CHNK, 1024, 0, stream>>>(ei, flags, sd, rank16, cnt);
  k_foldscan<<<FSB, 1024, 0, stream>>>(cnt, basecnt, rowptr, parts, flags + 2);
  k_scatgm<<<sgrid, 256, 0, stream>>>(sd, rank16, basecnt, rowptr, srcs,
                                      x, wt1, wa1, hbuf, asg, adg, gm1, flags);

  // layer 1 aggregation: 4x32 concat, relu
  k_agg<4, 32, true, false><<<ablocks, 256, 0, stream>>>(hbuf, asg, adg, rowptr, srcs, b1, flags, gm1, obuf, NODES);
  // layer 2: 128 -> 2x32 concat, relu
  k_gmfma<128, 64, 2, false><<<GBLK, 256, 0, stream>>>(obuf, wt2, wa2, hbuf, asg, adg, gm2, flags, NODES);
  k_agg<2, 32, true, false><<<ablocks, 256, 0, stream>>>(hbuf, asg, adg, rowptr, srcs, b2, flags, gm2, obuf, NODES);
  // layer 3: 64 -> 1x16 mean(=identity), out dtype follows input dtype
  k_gmfma<64, 16, 1, false><<<GBLK, 256, 0, stream>>>(obuf, wt3, wa3, hbuf, asg, adg, gm3, flags, NODES);
  k_agg<1, 16, false, true><<<ablocks, 256, 0, stream>>>(hbuf, asg, adg, rowptr, srcs, b3, flags, gm3, d_out, NODES);
}